// Round 1
// baseline (7985.082 us; speedup 1.0000x reference)
//
#include <hip/hip_runtime.h>
#include <math.h>

static constexpr int N  = 50000;
static constexpr int E  = 800000;
static constexpr int F  = 64;
static constexpr int R  = 20;
static constexpr int NL = 2;
static constexpr int B  = 64;
static constexpr float RC   = 5.0f;
static constexpr float LN2F = 0.6931471805599453f;
static constexpr float WIDTH  = RC / (R - 1);
static constexpr float INV2W2 = 1.0f / (2.0f * WIDTH * WIDTH);
static constexpr float PI_F = 3.14159265358979323846f;

// per-layer transposed-weight block: [UT 4096][VT 4096][aW1T 8192][aW2T 12288]
static constexpr int WT_PER_LAYER = 4096 + 4096 + 8192 + 12288; // 28672

__device__ __forceinline__ float ssp_f(float x) {
    // softplus(x) - log(2), numerically stable
    return fmaxf(x, 0.0f) + log1pf(__expf(-fabsf(x))) - LN2F;
}

__global__ void k_init_s(const int* __restrict__ z, const float* __restrict__ emb,
                         float* __restrict__ s) {
    int idx = blockIdx.x * blockDim.x + threadIdx.x;
    if (idx >= N * F) return;
    int i = idx >> 6, f = idx & 63;
    s[idx] = emb[z[i] * F + f];
}

__global__ void k_transpose(const float* __restrict__ U_W, const float* __restrict__ V_W,
                            const float* __restrict__ a_W1, const float* __restrict__ a_W2,
                            float* __restrict__ WT) {
    int tid = blockIdx.x * blockDim.x + threadIdx.x;
    if (tid >= NL * WT_PER_LAYER) return;
    int l = tid / WT_PER_LAYER;
    int r = tid % WT_PER_LAYER;
    float* base = WT + l * WT_PER_LAYER;
    if (r < 4096) {                       // UT[f*64+g] = U_W[g*64+f]
        int f = r >> 6, g = r & 63;
        base[r] = U_W[l * 4096 + g * 64 + f];
    } else if (r < 8192) {                // VT
        int o = r - 4096; int f = o >> 6, g = o & 63;
        base[r] = V_W[l * 4096 + g * 64 + f];
    } else if (r < 16384) {               // aW1T[j*64+g] = a_W1[g*128+j]
        int o = r - 8192; int j = o >> 6, g = o & 63;
        base[r] = a_W1[l * 8192 + g * 128 + j];
    } else {                              // aW2T[f*192+c] = a_W2[c*64+f]
        int o = r - 16384; int f = o / 192, c = o % 192;
        base[r] = a_W2[l * 12288 + c * 64 + f];
    }
}

// Edge/message kernel. Each wave owns one output block j in {0,1,2}:
//   j=0: m_s = W_s * phi_s     -> atomicAdd ds[src]
//   j=1: W_v * v[dst]          -> atomicAdd dv[src] (x3)
//   j=2: (W_r * phi_r) * r_hat -> atomicAdd dv[src] (x3)
// Lane g keeps weight columns W2[(64j+g)][:] and phiW[col][:] in registers.
__launch_bounds__(256, 2)
__global__ void k_edge(const float* __restrict__ pos, const int* __restrict__ ei,
                       const float* __restrict__ s, const float* __restrict__ v,
                       float* __restrict__ ds, float* __restrict__ dv,
                       const float* __restrict__ W1, const float* __restrict__ b1,
                       const float* __restrict__ W2, const float* __restrict__ b2,
                       const float* __restrict__ PW, const float* __restrict__ Pb) {
    __shared__ float W1T[R][F];      // W1T[r][f] = W1[f*R+r]
    __shared__ float h1buf[4][F];
    __shared__ float sbuf[4][F];
    for (int t = threadIdx.x; t < R * F; t += blockDim.x) {
        int r = t >> 6, f = t & 63;
        W1T[r][f] = W1[f * R + r];
    }
    __syncthreads();

    const int lane = threadIdx.x & 63;
    const int wid  = threadIdx.x >> 6;
    const int gw   = blockIdx.x * (blockDim.x >> 6) + wid;
    const int j    = gw % 3;
    const int estream = gw / 3;
    const int nstream = (gridDim.x * (blockDim.x >> 6)) / 3;

    float wf[F], wp[F];
    {
        const float* wrow = W2 + (j * 64 + lane) * 64;
        const int pcol = (j == 2) ? (128 + lane) : lane;   // phi_s for j0, phi_r for j2
        const float* prow = PW + pcol * 64;
        #pragma unroll
        for (int k = 0; k < F; k += 4) {
            float4 a = *(const float4*)(wrow + k);
            wf[k] = a.x; wf[k+1] = a.y; wf[k+2] = a.z; wf[k+3] = a.w;
            float4 bb = *(const float4*)(prow + k);
            wp[k] = bb.x; wp[k+1] = bb.y; wp[k+2] = bb.z; wp[k+3] = bb.w;
        }
    }
    const float bf  = b2[j * 64 + lane];
    const float bp  = (j == 2) ? Pb[128 + lane] : Pb[lane];
    const float b1l = b1[lane];

    for (int e = estream; e < E; e += nstream) {
        const int src = ei[e];
        const int dst = ei[E + e];
        float rx = pos[dst*3+0] - pos[src*3+0];
        float ry = pos[dst*3+1] - pos[src*3+1];
        float rz = pos[dst*3+2] - pos[src*3+2];
        float rn = sqrtf(rx*rx + ry*ry + rz*rz);
        float invn = 1.0f / fmaxf(rn, 1e-8f);
        float fc = (rn < RC) ? 0.5f * (__cosf(PI_F * rn * (1.0f/RC)) + 1.0f) : 0.0f;

        // h1[lane] = ssp(b1 + sum_r e_r * W1[lane][r])  (e_r wave-uniform, recomputed)
        float acc = b1l;
        #pragma unroll
        for (int r = 0; r < R; r++) {
            float dmu = rn - r * WIDTH;
            float er = __expf(-dmu * dmu * INV2W2) * fc;
            acc = fmaf(er, W1T[r][lane], acc);
        }
        float h1 = ssp_f(acc);
        h1buf[wid][lane] = h1;
        if (j != 1) sbuf[wid][lane] = s[dst * F + lane];

        float accf0 = bf, accf1 = 0.0f, accp0 = bp, accp1 = 0.0f;
        #pragma unroll
        for (int k = 0; k < F; k += 4) {
            float4 h4 = *(const float4*)&h1buf[wid][k];
            accf0 = fmaf(h4.x, wf[k],   accf0);
            accf1 = fmaf(h4.y, wf[k+1], accf1);
            accf0 = fmaf(h4.z, wf[k+2], accf0);
            accf1 = fmaf(h4.w, wf[k+3], accf1);
            if (j != 1) {
                float4 s4 = *(const float4*)&sbuf[wid][k];
                accp0 = fmaf(s4.x, wp[k],   accp0);
                accp1 = fmaf(s4.y, wp[k+1], accp1);
                accp0 = fmaf(s4.z, wp[k+2], accp0);
                accp1 = fmaf(s4.w, wp[k+3], accp1);
            }
        }
        float accf = accf0 + accf1;
        float accp = accp0 + accp1;

        if (j == 0) {
            atomicAdd(&ds[src * F + lane], accf * accp);
        } else if (j == 1) {
            #pragma unroll
            for (int d = 0; d < 3; d++) {
                float vd = v[(dst * 3 + d) * F + lane];
                atomicAdd(&dv[(src * 3 + d) * F + lane], accf * vd);
            }
        } else {
            float t = accf * accp;
            float rh[3] = {rx * invn, ry * invn, rz * invn};
            #pragma unroll
            for (int d = 0; d < 3; d++)
                atomicAdd(&dv[(src * 3 + d) * F + lane], t * rh[d]);
        }
    }
}

// Node update block: wave per node. Consumes ds/dv and re-zeroes them.
__launch_bounds__(1024, 1)
__global__ void k_update(float* __restrict__ s, float* __restrict__ v,
                         float* __restrict__ ds, float* __restrict__ dv,
                         const float* __restrict__ WT,
                         const float* __restrict__ ab1, const float* __restrict__ ab2) {
    const int lane = threadIdx.x & 63;
    const int wid  = threadIdx.x >> 6;
    const int gwave = blockIdx.x * (blockDim.x >> 6) + wid;
    const int nwaves = gridDim.x * (blockDim.x >> 6);
    const float* UT  = WT;
    const float* VT  = WT + 4096;
    const float* W1T = WT + 8192;
    const float* W2T = WT + 16384;

    __shared__ float sbuf[16][F];
    __shared__ float vbuf[16][3][F];
    __shared__ float nbuf[16][F];
    __shared__ float hbuf[16][F];

    const float ab1l  = ab1[lane];
    const float ab2_0 = ab2[lane], ab2_1 = ab2[64 + lane], ab2_2 = ab2[128 + lane];

    for (int n = gwave; n < N; n += nwaves) {
        float sn = s[n * F + lane] + ds[n * F + lane];
        ds[n * F + lane] = 0.0f;
        sbuf[wid][lane] = sn;
        float vn[3];
        #pragma unroll
        for (int d = 0; d < 3; d++) {
            int idx = (n * 3 + d) * F + lane;
            vn[d] = v[idx] + dv[idx];
            dv[idx] = 0.0f;
            vbuf[wid][d][lane] = vn[d];
        }
        float Uv[3] = {0,0,0}, Vv[3] = {0,0,0};
        #pragma unroll 8
        for (int f = 0; f < F; f++) {
            float u = UT[f * 64 + lane];
            float w = VT[f * 64 + lane];
            #pragma unroll
            for (int d = 0; d < 3; d++) {
                float vf = vbuf[wid][d][f];
                Uv[d] = fmaf(u, vf, Uv[d]);
                Vv[d] = fmaf(w, vf, Vv[d]);
            }
        }
        float vns   = Vv[0]*Vv[0] + Vv[1]*Vv[1] + Vv[2]*Vv[2];
        float inner = Uv[0]*Vv[0] + Uv[1]*Vv[1] + Uv[2]*Vv[2];
        nbuf[wid][lane] = vns;

        float x0 = ab1l, x1 = 0.0f;
        #pragma unroll 8
        for (int f = 0; f < F; f++) {
            x0 = fmaf(sbuf[wid][f], W1T[f * 64 + lane], x0);
            x1 = fmaf(nbuf[wid][f], W1T[(64 + f) * 64 + lane], x1);
        }
        float h = ssp_f(x0 + x1);
        hbuf[wid][lane] = h;
        float a0 = ab2_0, a1 = ab2_1, a2 = ab2_2;
        #pragma unroll 8
        for (int f = 0; f < F; f++) {
            float hf = hbuf[wid][f];
            a0 = fmaf(hf, W2T[f * 192 + lane],       a0);
            a1 = fmaf(hf, W2T[f * 192 + 64 + lane],  a1);
            a2 = fmaf(hf, W2T[f * 192 + 128 + lane], a2);
        }
        s[n * F + lane] = sn + a0 + a1 * inner;
        #pragma unroll
        for (int d = 0; d < 3; d++)
            v[(n * 3 + d) * F + lane] = vn[d] + a2 * Uv[d];
    }
}

__global__ void k_heads(const float* __restrict__ s, const float* __restrict__ v,
                        const int* __restrict__ batch_idx,
                        const float* __restrict__ eW1, const float* __restrict__ eb1,
                        const float* __restrict__ eW2, const float* __restrict__ eb2,
                        const float* __restrict__ dip_w,
                        float* __restrict__ eacc, float* __restrict__ macc) {
    __shared__ float se[B];
    __shared__ float sm[3][B];
    if (threadIdx.x < B) se[threadIdx.x] = 0.0f;
    if (threadIdx.x < 3 * B) sm[threadIdx.x >> 6][threadIdx.x & 63] = 0.0f;
    __syncthreads();
    int n = blockIdx.x * blockDim.x + threadIdx.x;
    if (n < N) {
        int b = batch_idx[n];
        float sr[F];
        #pragma unroll
        for (int f = 0; f < F; f += 4) {
            float4 t = *(const float4*)&s[n * F + f];
            sr[f] = t.x; sr[f+1] = t.y; sr[f+2] = t.z; sr[f+3] = t.w;
        }
        float eps = eb2[0];
        for (int jj = 0; jj < F / 2; jj++) {
            float acc = eb1[jj];
            #pragma unroll
            for (int f = 0; f < F; f++)
                acc = fmaf(sr[f], eW1[jj * F + f], acc);
            eps = fmaf(eW2[jj], ssp_f(acc), eps);
        }
        atomicAdd(&se[b], eps);
        #pragma unroll
        for (int d = 0; d < 3; d++) {
            float m = 0.0f;
            #pragma unroll 8
            for (int f = 0; f < F; f++)
                m = fmaf(v[(n * 3 + d) * F + f], dip_w[f], m);
            atomicAdd(&sm[d][b], m);
        }
    }
    __syncthreads();
    if (threadIdx.x < B) atomicAdd(&eacc[threadIdx.x], se[threadIdx.x]);
    if (threadIdx.x >= B && threadIdx.x < 4 * B) {
        int d = (threadIdx.x >> 6) - 1, b = threadIdx.x & 63;
        atomicAdd(&macc[d * B + b], sm[d][b]);
    }
}

__global__ void k_final(const float* __restrict__ eacc, const float* __restrict__ macc,
                        float* __restrict__ out) {
    int b = threadIdx.x;
    if (b < B) {
        out[b] = eacc[b];
        float mx = macc[b], my = macc[B + b], mz = macc[2 * B + b];
        out[B + b] = sqrtf(mx * mx + my * my + mz * mz);
    }
}

extern "C" void kernel_launch(void* const* d_in, const int* in_sizes, int n_in,
                              void* d_out, int out_size, void* d_ws, size_t ws_size,
                              hipStream_t stream) {
    const int*   z     = (const int*)d_in[0];
    const float* pos   = (const float*)d_in[1];
    const int*   ei    = (const int*)d_in[2];
    const int*   bidx  = (const int*)d_in[3];
    const float* emb   = (const float*)d_in[4];
    const float* phi_W = (const float*)d_in[5];
    const float* phi_b = (const float*)d_in[6];
    const float* fW1   = (const float*)d_in[7];
    const float* fb1   = (const float*)d_in[8];
    const float* fW2   = (const float*)d_in[9];
    const float* fb2   = (const float*)d_in[10];
    const float* U_W   = (const float*)d_in[11];
    const float* V_W   = (const float*)d_in[12];
    const float* aW1   = (const float*)d_in[13];
    const float* ab1   = (const float*)d_in[14];
    const float* aW2   = (const float*)d_in[15];
    const float* ab2   = (const float*)d_in[16];
    const float* eW1   = (const float*)d_in[17];
    const float* eb1   = (const float*)d_in[18];
    const float* eW2   = (const float*)d_in[19];
    const float* eb2   = (const float*)d_in[20];
    const float* dip_w = (const float*)d_in[21];
    float* out = (float*)d_out;

    float* ws  = (float*)d_ws;
    float* s    = ws;                              // N*64
    float* v    = s  + (size_t)N * F;              // N*192
    float* ds   = v  + (size_t)N * F * 3;          // N*64
    float* dv   = ds + (size_t)N * F;              // N*192
    float* WT   = dv + (size_t)N * F * 3;          // NL*28672
    float* eacc = WT + (size_t)NL * WT_PER_LAYER;  // B
    float* macc = eacc + B;                        // 3*B

    // fresh state every launch (ws is poisoned once and never re-poisoned)
    hipMemsetAsync(v,    0, sizeof(float) * (size_t)N * F * 3, stream);
    hipMemsetAsync(ds,   0, sizeof(float) * (size_t)N * F,     stream);
    hipMemsetAsync(dv,   0, sizeof(float) * (size_t)N * F * 3, stream);
    hipMemsetAsync(eacc, 0, sizeof(float) * 4 * B,             stream);
    hipMemsetAsync(out + 2 * B, 0, sizeof(float) * (size_t)N,  stream); // charges = 0

    k_init_s<<<(N * F + 255) / 256, 256, 0, stream>>>(z, emb, s);
    k_transpose<<<(NL * WT_PER_LAYER + 255) / 256, 256, 0, stream>>>(U_W, V_W, aW1, aW2, WT);

    for (int l = 0; l < NL; l++) {
        k_edge<<<768, 256, 0, stream>>>(pos, ei, s, v, ds, dv,
            fW1 + l * F * R, fb1 + l * F,
            fW2 + l * 192 * 64, fb2 + l * 192,
            phi_W + l * 192 * 64, phi_b + l * 192);
        k_update<<<256, 1024, 0, stream>>>(s, v, ds, dv,
            WT + l * WT_PER_LAYER, ab1 + l * F, ab2 + l * 192);
    }
    k_heads<<<(N + 255) / 256, 256, 0, stream>>>(s, v, bidx, eW1, eb1, eW2, eb2,
                                                 dip_w, eacc, macc);
    k_final<<<1, 64, 0, stream>>>(eacc, macc, out);
}

// Round 2
// 1095.769 us; speedup vs baseline: 7.2872x; 7.2872x over previous
//
#include <hip/hip_runtime.h>
#include <math.h>

static constexpr int N  = 50000;
static constexpr int E  = 800000;
static constexpr int F  = 64;
static constexpr int R  = 20;
static constexpr int NL = 2;
static constexpr int B  = 64;
static constexpr float RC   = 5.0f;
static constexpr float LN2F = 0.6931471805599453f;
static constexpr float WIDTH  = RC / (R - 1);
static constexpr float INV2W2 = 1.0f / (2.0f * WIDTH * WIDTH);
static constexpr float PI_F = 3.14159265358979323846f;

// filt(r) lookup table: NB intervals on [0,RC], rows NB+2 (last duplicated)
static constexpr int   NB     = 4096;
static constexpr float DR     = RC / NB;
static constexpr float INV_DR = NB / RC;
static constexpr int   TROWS  = NB + 2;

// per-layer transposed-weight block for update: [UT 4096][VT 4096][aW1T 8192][aW2T 12288]
static constexpr int WT_PER_LAYER = 4096 + 4096 + 8192 + 12288; // 28672

__device__ __forceinline__ float ssp_f(float x) {
    return fmaxf(x, 0.0f) + log1pf(__expf(-fabsf(x))) - LN2F;
}

__global__ void k_init_s(const int* __restrict__ z, const float* __restrict__ emb,
                         float* __restrict__ s) {
    int idx = blockIdx.x * blockDim.x + threadIdx.x;
    if (idx >= N * F) return;
    int i = idx >> 6, f = idx & 63;
    s[idx] = emb[z[i] * F + f];
}

// ---------- counting sort of edges by src ----------
__global__ void k_hist(const int* __restrict__ ei, int* __restrict__ cnt) {
    int e = blockIdx.x * blockDim.x + threadIdx.x;
    if (e < E) atomicAdd(&cnt[ei[e]], 1);
}

__global__ void k_scan(const int* __restrict__ cnt, int* __restrict__ off,
                       int* __restrict__ cur) {
    // single block, 1024 threads
    __shared__ int part[1024];
    const int t = threadIdx.x;
    const int CH = 49; // 1024*49 = 50176 >= N
    int s0 = 0;
    for (int j = 0; j < CH; j++) {
        int idx = t * CH + j;
        if (idx < N) s0 += cnt[idx];
    }
    part[t] = s0;
    __syncthreads();
    // inclusive Hillis-Steele scan
    for (int d = 1; d < 1024; d <<= 1) {
        int v = (t >= d) ? part[t - d] : 0;
        __syncthreads();
        part[t] += v;
        __syncthreads();
    }
    int run = part[t] - s0; // exclusive prefix
    for (int j = 0; j < CH; j++) {
        int idx = t * CH + j;
        if (idx < N) {
            off[idx] = run;
            cur[idx] = run;
            run += cnt[idx];
        }
    }
    if (t == 1023) off[N] = part[1023];
}

__global__ void k_scatter(const int* __restrict__ ei, int* __restrict__ cur,
                          int* __restrict__ dsts) {
    int e = blockIdx.x * blockDim.x + threadIdx.x;
    if (e < E) {
        int src = ei[e];
        int p = atomicAdd(&cur[src], 1);
        dsts[p] = ei[E + e];
    }
}

// ---------- filt(r) table: T[l][row*192 + c], row r = min(row,NB)*DR ----------
__global__ void k_table(const float* __restrict__ fW1, const float* __restrict__ fb1,
                        const float* __restrict__ fW2, const float* __restrict__ fb2,
                        float* __restrict__ T) {
    const int l   = blockIdx.x / TROWS;
    const int row = blockIdx.x % TROWS;
    const int lane = threadIdx.x; // block = 64
    const float r = fminf((float)row, (float)NB) * DR;
    const float fc = (r < RC) ? 0.5f * (__cosf(PI_F * r * (1.0f / RC)) + 1.0f) : 0.0f;

    __shared__ float sh[F];
    // h1[lane] = ssp(b1 + sum_r e_r * W1[lane][r])
    float acc = fb1[l * F + lane];
    const float* w1 = fW1 + (size_t)l * F * R + (size_t)lane * R;
    #pragma unroll
    for (int rr = 0; rr < R; rr++) {
        float dmu = r - rr * WIDTH;
        float er = __expf(-dmu * dmu * INV2W2) * fc;
        acc = fmaf(er, w1[rr], acc);
    }
    sh[lane] = ssp_f(acc);
    __syncthreads();
    // filt[c] = b2[c] + sum_k h1[k]*W2[c][k], c = lane, 64+lane, 128+lane
    float* Trow = T + ((size_t)l * TROWS + row) * 192;
    #pragma unroll
    for (int p = 0; p < 3; p++) {
        int c = p * 64 + lane;
        float a = fb2[l * 192 + c];
        const float* w2 = fW2 + ((size_t)l * 192 + c) * 64;
        #pragma unroll 8
        for (int k = 0; k < F; k++) a = fmaf(sh[k], w2[k], a);
        Trow[c] = a;
    }
}

// ---------- per-node phi_s / phi_r ----------
__launch_bounds__(256)
__global__ void k_phi(const float* __restrict__ s, const float* __restrict__ PW,
                      const float* __restrict__ Pb, float* __restrict__ phi) {
    __shared__ float sbuf[4][F];
    const int lane = threadIdx.x & 63;
    const int wid  = threadIdx.x >> 6;
    const int gwave = blockIdx.x * 4 + wid;
    const int nwaves = gridDim.x * 4;

    float ws[F], wr[F];
    {
        const float* rs = PW + (size_t)lane * 64;
        const float* rr = PW + (size_t)(128 + lane) * 64;
        #pragma unroll
        for (int k = 0; k < F; k += 4) {
            float4 a = *(const float4*)(rs + k);
            ws[k] = a.x; ws[k+1] = a.y; ws[k+2] = a.z; ws[k+3] = a.w;
            float4 b = *(const float4*)(rr + k);
            wr[k] = b.x; wr[k+1] = b.y; wr[k+2] = b.z; wr[k+3] = b.w;
        }
    }
    const float bs = Pb[lane], br = Pb[128 + lane];

    for (int n = gwave; n < N; n += nwaves) {
        sbuf[wid][lane] = s[(size_t)n * F + lane];
        float as = bs, ar = br;
        #pragma unroll
        for (int k = 0; k < F; k += 4) {
            float4 s4 = *(const float4*)&sbuf[wid][k];
            as = fmaf(s4.x, ws[k],   as); as = fmaf(s4.y, ws[k+1], as);
            as = fmaf(s4.z, ws[k+2], as); as = fmaf(s4.w, ws[k+3], as);
            ar = fmaf(s4.x, wr[k],   ar); ar = fmaf(s4.y, wr[k+1], ar);
            ar = fmaf(s4.z, wr[k+2], ar); ar = fmaf(s4.w, wr[k+3], ar);
        }
        phi[(size_t)n * 128 + lane]      = as;
        phi[(size_t)n * 128 + 64 + lane] = ar;
    }
}

// ---------- the gather/message kernel: wave per node, no atomics ----------
template<bool READV>
__launch_bounds__(256)
__global__ void k_gather(const float* __restrict__ pos, const int* __restrict__ dsts,
                         const int* __restrict__ off, const float* __restrict__ phi,
                         const float* __restrict__ T, const float* __restrict__ vin,
                         float* __restrict__ vout, float* __restrict__ s) {
    const int lane = threadIdx.x & 63;
    const int wid  = threadIdx.x >> 6;
    const int n = blockIdx.x * 4 + wid;
    if (n >= N) return;
    const int base = off[n], end = off[n + 1];
    const float px = pos[n * 3 + 0], py = pos[n * 3 + 1], pz = pos[n * 3 + 2];
    float ms = 0.f, mv0 = 0.f, mv1 = 0.f, mv2 = 0.f;

    for (int k = base; k < end; ++k) {
        const int dst = dsts[k];
        const float qx = pos[dst * 3 + 0] - px;
        const float qy = pos[dst * 3 + 1] - py;
        const float qz = pos[dst * 3 + 2] - pz;
        const float rn = sqrtf(qx * qx + qy * qy + qz * qz);
        const float invn = 1.0f / fmaxf(rn, 1e-8f);
        float t = rn * INV_DR;
        int i = (int)t;
        float fr = t - (float)i;
        if (i >= NB) { i = NB; fr = 0.f; }
        const float* r0 = T + (size_t)i * 192;
        const float w0s = r0[lane],       w1s = r0[192 + lane];
        const float w0v = r0[64 + lane],  w1v = r0[256 + lane];
        const float w0r = r0[128 + lane], w1r = r0[320 + lane];
        const float Ws = fmaf(fr, w1s - w0s, w0s);
        const float Wv = fmaf(fr, w1v - w0v, w0v);
        const float Wr = fmaf(fr, w1r - w0r, w0r);
        const float ps = phi[(size_t)dst * 128 + lane];
        const float pr = phi[(size_t)dst * 128 + 64 + lane];
        ms = fmaf(Ws, ps, ms);
        const float c = Wr * pr * invn;
        if (READV) {
            const float* vd = vin + (size_t)dst * 3 * F + lane;
            mv0 = fmaf(Wv, vd[0],     fmaf(c, qx, mv0));
            mv1 = fmaf(Wv, vd[F],     fmaf(c, qy, mv1));
            mv2 = fmaf(Wv, vd[2 * F], fmaf(c, qz, mv2));
        } else {
            mv0 = fmaf(c, qx, mv0);
            mv1 = fmaf(c, qy, mv1);
            mv2 = fmaf(c, qz, mv2);
        }
    }
    s[(size_t)n * F + lane] += ms;
    float* vo = vout + (size_t)n * 3 * F + lane;
    if (READV) {
        const float* vi = vin + (size_t)n * 3 * F + lane;
        vo[0]     = vi[0]     + mv0;
        vo[F]     = vi[F]     + mv1;
        vo[2 * F] = vi[2 * F] + mv2;
    } else {
        vo[0] = mv0; vo[F] = mv1; vo[2 * F] = mv2;
    }
}

// ---------- update-block weights transpose ----------
__global__ void k_transpose(const float* __restrict__ U_W, const float* __restrict__ V_W,
                            const float* __restrict__ a_W1, const float* __restrict__ a_W2,
                            float* __restrict__ WT) {
    int tid = blockIdx.x * blockDim.x + threadIdx.x;
    if (tid >= NL * WT_PER_LAYER) return;
    int l = tid / WT_PER_LAYER;
    int r = tid % WT_PER_LAYER;
    float* base = WT + l * WT_PER_LAYER;
    if (r < 4096) {                       // UT[f*64+g] = U_W[g*64+f]
        int f = r >> 6, g = r & 63;
        base[r] = U_W[l * 4096 + g * 64 + f];
    } else if (r < 8192) {                // VT
        int o = r - 4096; int f = o >> 6, g = o & 63;
        base[r] = V_W[l * 4096 + g * 64 + f];
    } else if (r < 16384) {               // aW1T[j*64+g] = a_W1[g*128+j]
        int o = r - 8192; int j = o >> 6, g = o & 63;
        base[r] = a_W1[l * 8192 + g * 128 + j];
    } else {                              // aW2T[f*192+c] = a_W2[c*64+f]
        int o = r - 16384; int f = o / 192, c = o % 192;
        base[r] = a_W2[l * 12288 + c * 64 + f];
    }
}

// ---------- node update block (s, v already include message sums) ----------
__launch_bounds__(1024, 1)
__global__ void k_update(float* __restrict__ s, float* __restrict__ v,
                         const float* __restrict__ WT,
                         const float* __restrict__ ab1, const float* __restrict__ ab2) {
    const int lane = threadIdx.x & 63;
    const int wid  = threadIdx.x >> 6;
    const int gwave = blockIdx.x * (blockDim.x >> 6) + wid;
    const int nwaves = gridDim.x * (blockDim.x >> 6);
    const float* UT  = WT;
    const float* VT  = WT + 4096;
    const float* W1T = WT + 8192;
    const float* W2T = WT + 16384;

    __shared__ float sbuf[16][F];
    __shared__ float vbuf[16][3][F];
    __shared__ float nbuf[16][F];
    __shared__ float hbuf[16][F];

    const float ab1l  = ab1[lane];
    const float ab2_0 = ab2[lane], ab2_1 = ab2[64 + lane], ab2_2 = ab2[128 + lane];

    for (int n = gwave; n < N; n += nwaves) {
        float sn = s[(size_t)n * F + lane];
        sbuf[wid][lane] = sn;
        float vn[3];
        #pragma unroll
        for (int d = 0; d < 3; d++) {
            vn[d] = v[((size_t)n * 3 + d) * F + lane];
            vbuf[wid][d][lane] = vn[d];
        }
        float Uv[3] = {0,0,0}, Vv[3] = {0,0,0};
        #pragma unroll 8
        for (int f = 0; f < F; f++) {
            float u = UT[f * 64 + lane];
            float w = VT[f * 64 + lane];
            #pragma unroll
            for (int d = 0; d < 3; d++) {
                float vf = vbuf[wid][d][f];
                Uv[d] = fmaf(u, vf, Uv[d]);
                Vv[d] = fmaf(w, vf, Vv[d]);
            }
        }
        float vns   = Vv[0]*Vv[0] + Vv[1]*Vv[1] + Vv[2]*Vv[2];
        float inner = Uv[0]*Vv[0] + Uv[1]*Vv[1] + Uv[2]*Vv[2];
        nbuf[wid][lane] = vns;

        float x0 = ab1l, x1 = 0.0f;
        #pragma unroll 8
        for (int f = 0; f < F; f++) {
            x0 = fmaf(sbuf[wid][f], W1T[f * 64 + lane], x0);
            x1 = fmaf(nbuf[wid][f], W1T[(64 + f) * 64 + lane], x1);
        }
        float h = ssp_f(x0 + x1);
        hbuf[wid][lane] = h;
        float a0 = ab2_0, a1 = ab2_1, a2 = ab2_2;
        #pragma unroll 8
        for (int f = 0; f < F; f++) {
            float hf = hbuf[wid][f];
            a0 = fmaf(hf, W2T[f * 192 + lane],       a0);
            a1 = fmaf(hf, W2T[f * 192 + 64 + lane],  a1);
            a2 = fmaf(hf, W2T[f * 192 + 128 + lane], a2);
        }
        s[(size_t)n * F + lane] = sn + a0 + a1 * inner;
        #pragma unroll
        for (int d = 0; d < 3; d++)
            v[((size_t)n * 3 + d) * F + lane] = vn[d] + a2 * Uv[d];
    }
}

__global__ void k_heads(const float* __restrict__ s, const float* __restrict__ v,
                        const int* __restrict__ batch_idx,
                        const float* __restrict__ eW1, const float* __restrict__ eb1,
                        const float* __restrict__ eW2, const float* __restrict__ eb2,
                        const float* __restrict__ dip_w,
                        float* __restrict__ eacc, float* __restrict__ macc) {
    __shared__ float se[B];
    __shared__ float sm[3][B];
    if (threadIdx.x < B) se[threadIdx.x] = 0.0f;
    if (threadIdx.x < 3 * B) sm[threadIdx.x >> 6][threadIdx.x & 63] = 0.0f;
    __syncthreads();
    int n = blockIdx.x * blockDim.x + threadIdx.x;
    if (n < N) {
        int b = batch_idx[n];
        float sr[F];
        #pragma unroll
        for (int f = 0; f < F; f += 4) {
            float4 t = *(const float4*)&s[(size_t)n * F + f];
            sr[f] = t.x; sr[f+1] = t.y; sr[f+2] = t.z; sr[f+3] = t.w;
        }
        float eps = eb2[0];
        for (int jj = 0; jj < F / 2; jj++) {
            float acc = eb1[jj];
            #pragma unroll
            for (int f = 0; f < F; f++)
                acc = fmaf(sr[f], eW1[jj * F + f], acc);
            eps = fmaf(eW2[jj], ssp_f(acc), eps);
        }
        atomicAdd(&se[b], eps);
        #pragma unroll
        for (int d = 0; d < 3; d++) {
            float m = 0.0f;
            #pragma unroll 8
            for (int f = 0; f < F; f++)
                m = fmaf(v[((size_t)n * 3 + d) * F + f], dip_w[f], m);
            atomicAdd(&sm[d][b], m);
        }
    }
    __syncthreads();
    if (threadIdx.x < B) atomicAdd(&eacc[threadIdx.x], se[threadIdx.x]);
    if (threadIdx.x >= B && threadIdx.x < 4 * B) {
        int d = (threadIdx.x >> 6) - 1, b = threadIdx.x & 63;
        atomicAdd(&macc[d * B + b], sm[d][b]);
    }
}

__global__ void k_final(const float* __restrict__ eacc, const float* __restrict__ macc,
                        float* __restrict__ out) {
    int b = threadIdx.x;
    if (b < B) {
        out[b] = eacc[b];
        float mx = macc[b], my = macc[B + b], mz = macc[2 * B + b];
        out[B + b] = sqrtf(mx * mx + my * my + mz * mz);
    }
}

extern "C" void kernel_launch(void* const* d_in, const int* in_sizes, int n_in,
                              void* d_out, int out_size, void* d_ws, size_t ws_size,
                              hipStream_t stream) {
    const int*   z     = (const int*)d_in[0];
    const float* pos   = (const float*)d_in[1];
    const int*   ei    = (const int*)d_in[2];
    const int*   bidx  = (const int*)d_in[3];
    const float* emb   = (const float*)d_in[4];
    const float* phi_W = (const float*)d_in[5];
    const float* phi_b = (const float*)d_in[6];
    const float* fW1   = (const float*)d_in[7];
    const float* fb1   = (const float*)d_in[8];
    const float* fW2   = (const float*)d_in[9];
    const float* fb2   = (const float*)d_in[10];
    const float* U_W   = (const float*)d_in[11];
    const float* V_W   = (const float*)d_in[12];
    const float* aW1   = (const float*)d_in[13];
    const float* ab1   = (const float*)d_in[14];
    const float* aW2   = (const float*)d_in[15];
    const float* ab2   = (const float*)d_in[16];
    const float* eW1   = (const float*)d_in[17];
    const float* eb1   = (const float*)d_in[18];
    const float* eW2   = (const float*)d_in[19];
    const float* eb2   = (const float*)d_in[20];
    const float* dip_w = (const float*)d_in[21];
    float* out = (float*)d_out;

    // ---- workspace carve-up ----
    float* ws = (float*)d_ws;
    float* s    = ws;                                  // N*64
    float* vA   = s    + (size_t)N * F;                // N*192
    float* vB   = vA   + (size_t)N * F * 3;            // N*192
    float* phi  = vB   + (size_t)N * F * 3;            // N*128
    float* T    = phi  + (size_t)N * 128;              // NL*TROWS*192
    float* WT   = T    + (size_t)NL * TROWS * 192;     // NL*28672
    float* eacc = WT   + (size_t)NL * WT_PER_LAYER;    // B
    float* macc = eacc + B;                            // 3B
    int*   cnt  = (int*)(macc + 3 * B);                // N
    int*   off  = cnt  + N;                            // N+1
    int*   cur  = off  + N + 1;                        // N
    int*   dsts = cur  + N;                            // E

    hipMemsetAsync(cnt,  0, sizeof(int) * N, stream);
    hipMemsetAsync(eacc, 0, sizeof(float) * 4 * B, stream);
    hipMemsetAsync(out + 2 * B, 0, sizeof(float) * (size_t)N, stream); // charges

    k_init_s<<<(N * F + 255) / 256, 256, 0, stream>>>(z, emb, s);
    k_hist<<<(E + 255) / 256, 256, 0, stream>>>(ei, cnt);
    k_scan<<<1, 1024, 0, stream>>>(cnt, off, cur);
    k_scatter<<<(E + 255) / 256, 256, 0, stream>>>(ei, cur, dsts);
    k_table<<<NL * TROWS, 64, 0, stream>>>(fW1, fb1, fW2, fb2, T);
    k_transpose<<<(NL * WT_PER_LAYER + 255) / 256, 256, 0, stream>>>(U_W, V_W, aW1, aW2, WT);

    const int gblocks = (N + 3) / 4;
    // layer 0 (v == 0: skip v gather)
    k_phi<<<512, 256, 0, stream>>>(s, phi_W, phi_b, phi);
    k_gather<false><<<gblocks, 256, 0, stream>>>(pos, dsts, off, phi,
        T, nullptr, vA, s);
    k_update<<<256, 1024, 0, stream>>>(s, vA, WT, ab1, ab2);
    // layer 1
    k_phi<<<512, 256, 0, stream>>>(s, phi_W + (size_t)192 * 64, phi_b + 192, phi);
    k_gather<true><<<gblocks, 256, 0, stream>>>(pos, dsts, off, phi,
        T + (size_t)TROWS * 192, vA, vB, s);
    k_update<<<256, 1024, 0, stream>>>(s, vB, WT + WT_PER_LAYER, ab1 + F, ab2 + 192);

    k_heads<<<(N + 255) / 256, 256, 0, stream>>>(s, vB, bidx, eW1, eb1, eW2, eb2,
                                                 dip_w, eacc, macc);
    k_final<<<1, 64, 0, stream>>>(eacc, macc, out);
}

// Round 3
// 802.549 us; speedup vs baseline: 9.9497x; 1.3654x over previous
//
#include <hip/hip_runtime.h>
#include <math.h>

static constexpr int N  = 50000;
static constexpr int E  = 800000;
static constexpr int F  = 64;
static constexpr int R  = 20;
static constexpr int NL = 2;
static constexpr int B  = 64;
static constexpr float RC   = 5.0f;
static constexpr float LN2F = 0.6931471805599453f;
static constexpr float WIDTH  = RC / (R - 1);
static constexpr float INV2W2 = 1.0f / (2.0f * WIDTH * WIDTH);
static constexpr float PI_F = 3.14159265358979323846f;

// filt(r) lookup table: NB intervals on [0,RC], rows NB+2 (last duplicated)
static constexpr int   NB     = 4096;
static constexpr float DR     = RC / NB;
static constexpr float INV_DR = NB / RC;
static constexpr int   TROWS  = NB + 2;

typedef __attribute__((ext_vector_type(8))) short bf16x8;
typedef __attribute__((ext_vector_type(4))) float f32x4;

__device__ __forceinline__ float ssp_f(float x) {
    return fmaxf(x, 0.0f) + log1pf(__expf(-fabsf(x))) - LN2F;
}

__device__ __forceinline__ short f2bf(float x) {
    unsigned u = __builtin_bit_cast(unsigned, x);
    unsigned r = (u + 0x7fffu + ((u >> 16) & 1u)) >> 16;
    return (short)r;
}

__global__ void k_init_s(const int* __restrict__ z, const float* __restrict__ emb,
                         float* __restrict__ s) {
    int idx = blockIdx.x * blockDim.x + threadIdx.x;
    if (idx >= N * F) return;
    int i = idx >> 6, f = idx & 63;
    s[idx] = emb[z[i] * F + f];
}

// ---------- counting sort of edges by src ----------
__global__ void k_hist(const int* __restrict__ ei, int* __restrict__ cnt) {
    int e = blockIdx.x * blockDim.x + threadIdx.x;
    if (e < E) atomicAdd(&cnt[ei[e]], 1);
}

__global__ void k_scan(const int* __restrict__ cnt, int* __restrict__ off,
                       int* __restrict__ cur) {
    __shared__ int part[1024];
    const int t = threadIdx.x;
    const int CH = 49; // 1024*49 = 50176 >= N
    int s0 = 0;
    for (int j = 0; j < CH; j++) {
        int idx = t * CH + j;
        if (idx < N) s0 += cnt[idx];
    }
    part[t] = s0;
    __syncthreads();
    for (int d = 1; d < 1024; d <<= 1) {
        int v = (t >= d) ? part[t - d] : 0;
        __syncthreads();
        part[t] += v;
        __syncthreads();
    }
    int run = part[t] - s0; // exclusive prefix
    for (int j = 0; j < CH; j++) {
        int idx = t * CH + j;
        if (idx < N) {
            off[idx] = run;
            cur[idx] = run;
            run += cnt[idx];
        }
    }
    if (t == 1023) off[N] = part[1023];
}

__global__ void k_scatter(const int* __restrict__ ei, int* __restrict__ cur,
                          int* __restrict__ dsts) {
    int e = blockIdx.x * blockDim.x + threadIdx.x;
    if (e < E) {
        int src = ei[e];
        int p = atomicAdd(&cur[src], 1);
        dsts[p] = ei[E + e];
    }
}

// ---------- filt(r) table ----------
__global__ void k_table(const float* __restrict__ fW1, const float* __restrict__ fb1,
                        const float* __restrict__ fW2, const float* __restrict__ fb2,
                        float* __restrict__ T) {
    const int l   = blockIdx.x / TROWS;
    const int row = blockIdx.x % TROWS;
    const int lane = threadIdx.x; // block = 64
    const float r = fminf((float)row, (float)NB) * DR;
    const float fc = (r < RC) ? 0.5f * (__cosf(PI_F * r * (1.0f / RC)) + 1.0f) : 0.0f;

    __shared__ float sh[F];
    float acc = fb1[l * F + lane];
    const float* w1 = fW1 + (size_t)l * F * R + (size_t)lane * R;
    #pragma unroll
    for (int rr = 0; rr < R; rr++) {
        float dmu = r - rr * WIDTH;
        float er = __expf(-dmu * dmu * INV2W2) * fc;
        acc = fmaf(er, w1[rr], acc);
    }
    sh[lane] = ssp_f(acc);
    __syncthreads();
    float* Trow = T + ((size_t)l * TROWS + row) * 192;
    #pragma unroll
    for (int p = 0; p < 3; p++) {
        int c = p * 64 + lane;
        float a = fb2[l * 192 + c];
        const float* w2 = fW2 + ((size_t)l * 192 + c) * 64;
        #pragma unroll 8
        for (int k = 0; k < F; k++) a = fmaf(sh[k], w2[k], a);
        Trow[c] = a;
    }
}

// ---------- per-node phi_s / phi_r ----------
__launch_bounds__(256)
__global__ void k_phi(const float* __restrict__ s, const float* __restrict__ PW,
                      const float* __restrict__ Pb, float* __restrict__ phi) {
    __shared__ float sbuf[4][F];
    const int lane = threadIdx.x & 63;
    const int wid  = threadIdx.x >> 6;
    const int gwave = blockIdx.x * 4 + wid;
    const int nwaves = gridDim.x * 4;

    float ws[F], wr[F];
    {
        const float* rs = PW + (size_t)lane * 64;
        const float* rr = PW + (size_t)(128 + lane) * 64;
        #pragma unroll
        for (int k = 0; k < F; k += 4) {
            float4 a = *(const float4*)(rs + k);
            ws[k] = a.x; ws[k+1] = a.y; ws[k+2] = a.z; ws[k+3] = a.w;
            float4 b = *(const float4*)(rr + k);
            wr[k] = b.x; wr[k+1] = b.y; wr[k+2] = b.z; wr[k+3] = b.w;
        }
    }
    const float bs = Pb[lane], br = Pb[128 + lane];

    for (int n = gwave; n < N; n += nwaves) {
        sbuf[wid][lane] = s[(size_t)n * F + lane];
        float as = bs, ar = br;
        #pragma unroll
        for (int k = 0; k < F; k += 4) {
            float4 s4 = *(const float4*)&sbuf[wid][k];
            as = fmaf(s4.x, ws[k],   as); as = fmaf(s4.y, ws[k+1], as);
            as = fmaf(s4.z, ws[k+2], as); as = fmaf(s4.w, ws[k+3], as);
            ar = fmaf(s4.x, wr[k],   ar); ar = fmaf(s4.y, wr[k+1], ar);
            ar = fmaf(s4.z, wr[k+2], ar); ar = fmaf(s4.w, wr[k+3], ar);
        }
        phi[(size_t)n * 128 + lane]      = as;
        phi[(size_t)n * 128 + 64 + lane] = ar;
    }
}

// ---------- gather/message kernel: wave per node, no atomics ----------
template<bool READV>
__launch_bounds__(256)
__global__ void k_gather(const float* __restrict__ pos, const int* __restrict__ dsts,
                         const int* __restrict__ off, const float* __restrict__ phi,
                         const float* __restrict__ T, const float* __restrict__ vin,
                         float* __restrict__ vout, float* __restrict__ s) {
    const int lane = threadIdx.x & 63;
    const int wid  = threadIdx.x >> 6;
    const int n = blockIdx.x * 4 + wid;
    if (n >= N) return;
    const int base = off[n], end = off[n + 1];
    const float px = pos[n * 3 + 0], py = pos[n * 3 + 1], pz = pos[n * 3 + 2];
    float ms = 0.f, mv0 = 0.f, mv1 = 0.f, mv2 = 0.f;

    for (int k = base; k < end; ++k) {
        const int dst = dsts[k];
        const float qx = pos[dst * 3 + 0] - px;
        const float qy = pos[dst * 3 + 1] - py;
        const float qz = pos[dst * 3 + 2] - pz;
        const float rn = sqrtf(qx * qx + qy * qy + qz * qz);
        const float invn = 1.0f / fmaxf(rn, 1e-8f);
        float t = rn * INV_DR;
        int i = (int)t;
        float fr = t - (float)i;
        if (i >= NB) { i = NB; fr = 0.f; }
        const float* r0 = T + (size_t)i * 192;
        const float w0s = r0[lane],       w1s = r0[192 + lane];
        const float w0v = r0[64 + lane],  w1v = r0[256 + lane];
        const float w0r = r0[128 + lane], w1r = r0[320 + lane];
        const float Ws = fmaf(fr, w1s - w0s, w0s);
        const float Wv = fmaf(fr, w1v - w0v, w0v);
        const float Wr = fmaf(fr, w1r - w0r, w0r);
        const float ps = phi[(size_t)dst * 128 + lane];
        const float pr = phi[(size_t)dst * 128 + 64 + lane];
        ms = fmaf(Ws, ps, ms);
        const float c = Wr * pr * invn;
        if (READV) {
            const float* vd = vin + (size_t)dst * 3 * F + lane;
            mv0 = fmaf(Wv, vd[0],     fmaf(c, qx, mv0));
            mv1 = fmaf(Wv, vd[F],     fmaf(c, qy, mv1));
            mv2 = fmaf(Wv, vd[2 * F], fmaf(c, qz, mv2));
        } else {
            mv0 = fmaf(c, qx, mv0);
            mv1 = fmaf(c, qy, mv1);
            mv2 = fmaf(c, qz, mv2);
        }
    }
    s[(size_t)n * F + lane] += ms;
    float* vo = vout + (size_t)n * 3 * F + lane;
    if (READV) {
        const float* vi = vin + (size_t)n * 3 * F + lane;
        vo[0]     = vi[0]     + mv0;
        vo[F]     = vi[F]     + mv1;
        vo[2 * F] = vi[2 * F] + mv2;
    } else {
        vo[0] = mv0; vo[F] = mv1; vo[2 * F] = mv2;
    }
}

// ---------- MFMA node-update block ----------
// 32 nodes/block, 4 waves; wave w owns output g-slice [16w, 16w+16).
// GEMM1: (96=3d*32n rows x K=64) @ U/V -> Uv,Vv; vns/inner via register combine.
// GEMM2: x=[s|vns] (32xK=128) @ a_W1^T -> ssp -> h. GEMM3: h @ a_W2^T (N=192).
__device__ __forceinline__ bf16x8 load_wfrag(const float* __restrict__ Wp, int ldk,
                                             int nrow, int k0) {
    const float* p = Wp + (size_t)nrow * ldk + k0;
    float4 a = *(const float4*)p;
    float4 b = *(const float4*)(p + 4);
    bf16x8 r;
    r[0] = f2bf(a.x); r[1] = f2bf(a.y); r[2] = f2bf(a.z); r[3] = f2bf(a.w);
    r[4] = f2bf(b.x); r[5] = f2bf(b.y); r[6] = f2bf(b.z); r[7] = f2bf(b.w);
    return r;
}

__launch_bounds__(256)
__global__ void k_update_mfma(float* __restrict__ s, float* __restrict__ v,
                              const float* __restrict__ U_W, const float* __restrict__ V_W,
                              const float* __restrict__ aW1, const float* __restrict__ ab1,
                              const float* __restrict__ aW2, const float* __restrict__ ab2) {
    __shared__ short vlds[96 * 72];   // [row=d*32+nn][f], pad 8
    __shared__ short xlds[32 * 136];  // [nn][0:64 s | 64:128 vns], pad 8
    __shared__ short hlds[32 * 72];   // [nn][c], pad 8

    const int tid = threadIdx.x;
    const int l   = tid & 63;
    const int w   = tid >> 6;       // wave 0..3
    const int lo  = l & 15;
    const int hi  = l >> 4;         // 0..3
    const int n0  = blockIdx.x * 32;

    // --- preload weight B-fragments (lane holds W[n][k0+hi*8 .. +7]) ---
    bf16x8 ufr[2], vfr[2], w1fr[4], w2fr[3][2];
    #pragma unroll
    for (int kk = 0; kk < 2; kk++) {
        ufr[kk] = load_wfrag(U_W, 64, w * 16 + lo, kk * 32 + hi * 8);
        vfr[kk] = load_wfrag(V_W, 64, w * 16 + lo, kk * 32 + hi * 8);
    }
    #pragma unroll
    for (int kk = 0; kk < 4; kk++)
        w1fr[kk] = load_wfrag(aW1, 128, w * 16 + lo, kk * 32 + hi * 8);
    #pragma unroll
    for (int p = 0; p < 3; p++)
        #pragma unroll
        for (int kk = 0; kk < 2; kk++)
            w2fr[p][kk] = load_wfrag(aW2, 64, p * 64 + w * 16 + lo, kk * 32 + hi * 8);

    // --- stage v (bf16) into vlds, s (bf16) into xlds[:,0:64] ---
    for (int u = tid; u < 96 * 8; u += 256) {
        int row = u >> 3, oct = u & 7;
        int d = row >> 5, nn = row & 31;
        int n = min(n0 + nn, N - 1);
        const float* src = v + ((size_t)n * 3 + d) * 64 + oct * 8;
        float4 a = *(const float4*)src;
        float4 b = *(const float4*)(src + 4);
        bf16x8 t;
        t[0] = f2bf(a.x); t[1] = f2bf(a.y); t[2] = f2bf(a.z); t[3] = f2bf(a.w);
        t[4] = f2bf(b.x); t[5] = f2bf(b.y); t[6] = f2bf(b.z); t[7] = f2bf(b.w);
        *(bf16x8*)&vlds[row * 72 + oct * 8] = t;
    }
    for (int u = tid; u < 32 * 8; u += 256) {
        int nn = u >> 3, oct = u & 7;
        int n = min(n0 + nn, N - 1);
        const float* src = s + (size_t)n * 64 + oct * 8;
        float4 a = *(const float4*)src;
        float4 b = *(const float4*)(src + 4);
        bf16x8 t;
        t[0] = f2bf(a.x); t[1] = f2bf(a.y); t[2] = f2bf(a.z); t[3] = f2bf(a.w);
        t[4] = f2bf(b.x); t[5] = f2bf(b.y); t[6] = f2bf(b.z); t[7] = f2bf(b.w);
        *(bf16x8*)&xlds[nn * 136 + oct * 8] = t;
    }
    __syncthreads();

    // --- GEMM1: rows (d,nn) x g ---
    f32x4 cu[6], cv[6];
    #pragma unroll
    for (int mt = 0; mt < 6; mt++) { cu[mt] = (f32x4)0.0f; cv[mt] = (f32x4)0.0f; }
    #pragma unroll
    for (int kk = 0; kk < 2; kk++) {
        #pragma unroll
        for (int mt = 0; mt < 6; mt++) {
            bf16x8 af = *(const bf16x8*)&vlds[(mt * 16 + lo) * 72 + kk * 32 + hi * 8];
            cu[mt] = __builtin_amdgcn_mfma_f32_16x16x32_bf16(af, ufr[kk], cu[mt], 0, 0, 0);
            cv[mt] = __builtin_amdgcn_mfma_f32_16x16x32_bf16(af, vfr[kk], cv[mt], 0, 0, 0);
        }
    }

    // vns -> xlds[:,64:128] (bf16), inner kept in regs
    f32x4 inn[2];
    #pragma unroll
    for (int nt = 0; nt < 2; nt++) {
        #pragma unroll
        for (int r = 0; r < 4; r++) {
            float vs = 0.f, ii = 0.f;
            #pragma unroll
            for (int d = 0; d < 3; d++) {
                float a = cu[d * 2 + nt][r], b = cv[d * 2 + nt][r];
                vs = fmaf(b, b, vs);
                ii = fmaf(a, b, ii);
            }
            inn[nt][r] = ii;
            int nl = nt * 16 + hi * 4 + r;
            xlds[nl * 136 + 64 + w * 16 + lo] = f2bf(vs);
        }
    }
    __syncthreads();

    // --- GEMM2: x(32x128) @ W1 -> ssp -> hlds ---
    f32x4 c2[2];
    c2[0] = (f32x4)0.0f; c2[1] = (f32x4)0.0f;
    #pragma unroll
    for (int kk = 0; kk < 4; kk++) {
        #pragma unroll
        for (int mt = 0; mt < 2; mt++) {
            bf16x8 af = *(const bf16x8*)&xlds[(mt * 16 + lo) * 136 + kk * 32 + hi * 8];
            c2[mt] = __builtin_amdgcn_mfma_f32_16x16x32_bf16(af, w1fr[kk], c2[mt], 0, 0, 0);
        }
    }
    {
        const float ab1c = ab1[w * 16 + lo];
        #pragma unroll
        for (int mt = 0; mt < 2; mt++)
            #pragma unroll
            for (int r = 0; r < 4; r++) {
                float hv = ssp_f(c2[mt][r] + ab1c);
                hlds[(mt * 16 + hi * 4 + r) * 72 + w * 16 + lo] = f2bf(hv);
            }
    }
    __syncthreads();

    // --- GEMM3: h(32x64) @ W2 (192 cols; wave w owns col sets {16w, 64+16w, 128+16w}) ---
    f32x4 c3[2][3];
    #pragma unroll
    for (int mt = 0; mt < 2; mt++)
        #pragma unroll
        for (int p = 0; p < 3; p++) c3[mt][p] = (f32x4)0.0f;
    #pragma unroll
    for (int kk = 0; kk < 2; kk++) {
        #pragma unroll
        for (int mt = 0; mt < 2; mt++) {
            bf16x8 af = *(const bf16x8*)&hlds[(mt * 16 + lo) * 72 + kk * 32 + hi * 8];
            #pragma unroll
            for (int p = 0; p < 3; p++)
                c3[mt][p] = __builtin_amdgcn_mfma_f32_16x16x32_bf16(af, w2fr[p][kk], c3[mt][p], 0, 0, 0);
        }
    }

    // --- epilogue: s,v RMW in f32 ---
    const float ab2c0 = ab2[w * 16 + lo];
    const float ab2c1 = ab2[64 + w * 16 + lo];
    const float ab2c2 = ab2[128 + w * 16 + lo];
    const int g = w * 16 + lo;
    #pragma unroll
    for (int mt = 0; mt < 2; mt++) {
        #pragma unroll
        for (int r = 0; r < 4; r++) {
            int n = n0 + mt * 16 + hi * 4 + r;
            if (n >= N) continue;
            float a_ss = c3[mt][0][r] + ab2c0;
            float a_sv = c3[mt][1][r] + ab2c1;
            float a_vv = c3[mt][2][r] + ab2c2;
            size_t si = (size_t)n * 64 + g;
            s[si] = s[si] + a_ss + a_sv * inn[mt][r];
            #pragma unroll
            for (int d = 0; d < 3; d++) {
                size_t vi = ((size_t)n * 3 + d) * 64 + g;
                v[vi] = v[vi] + a_vv * cu[d * 2 + mt][r];
            }
        }
    }
}

__global__ void k_heads(const float* __restrict__ s, const float* __restrict__ v,
                        const int* __restrict__ batch_idx,
                        const float* __restrict__ eW1, const float* __restrict__ eb1,
                        const float* __restrict__ eW2, const float* __restrict__ eb2,
                        const float* __restrict__ dip_w,
                        float* __restrict__ eacc, float* __restrict__ macc) {
    __shared__ float se[B];
    __shared__ float sm[3][B];
    if (threadIdx.x < B) se[threadIdx.x] = 0.0f;
    if (threadIdx.x < 3 * B) sm[threadIdx.x >> 6][threadIdx.x & 63] = 0.0f;
    __syncthreads();
    int n = blockIdx.x * blockDim.x + threadIdx.x;
    if (n < N) {
        int b = batch_idx[n];
        float sr[F];
        #pragma unroll
        for (int f = 0; f < F; f += 4) {
            float4 t = *(const float4*)&s[(size_t)n * F + f];
            sr[f] = t.x; sr[f+1] = t.y; sr[f+2] = t.z; sr[f+3] = t.w;
        }
        float eps = eb2[0];
        for (int jj = 0; jj < F / 2; jj++) {
            float acc = eb1[jj];
            #pragma unroll
            for (int f = 0; f < F; f++)
                acc = fmaf(sr[f], eW1[jj * F + f], acc);
            eps = fmaf(eW2[jj], ssp_f(acc), eps);
        }
        atomicAdd(&se[b], eps);
        #pragma unroll
        for (int d = 0; d < 3; d++) {
            float m = 0.0f;
            #pragma unroll 8
            for (int f = 0; f < F; f++)
                m = fmaf(v[((size_t)n * 3 + d) * F + f], dip_w[f], m);
            atomicAdd(&sm[d][b], m);
        }
    }
    __syncthreads();
    if (threadIdx.x < B) atomicAdd(&eacc[threadIdx.x], se[threadIdx.x]);
    if (threadIdx.x >= B && threadIdx.x < 4 * B) {
        int d = (threadIdx.x >> 6) - 1, b = threadIdx.x & 63;
        atomicAdd(&macc[d * B + b], sm[d][b]);
    }
}

__global__ void k_final(const float* __restrict__ eacc, const float* __restrict__ macc,
                        float* __restrict__ out) {
    int b = threadIdx.x;
    if (b < B) {
        out[b] = eacc[b];
        float mx = macc[b], my = macc[B + b], mz = macc[2 * B + b];
        out[B + b] = sqrtf(mx * mx + my * my + mz * mz);
    }
}

extern "C" void kernel_launch(void* const* d_in, const int* in_sizes, int n_in,
                              void* d_out, int out_size, void* d_ws, size_t ws_size,
                              hipStream_t stream) {
    const int*   z     = (const int*)d_in[0];
    const float* pos   = (const float*)d_in[1];
    const int*   ei    = (const int*)d_in[2];
    const int*   bidx  = (const int*)d_in[3];
    const float* emb   = (const float*)d_in[4];
    const float* phi_W = (const float*)d_in[5];
    const float* phi_b = (const float*)d_in[6];
    const float* fW1   = (const float*)d_in[7];
    const float* fb1   = (const float*)d_in[8];
    const float* fW2   = (const float*)d_in[9];
    const float* fb2   = (const float*)d_in[10];
    const float* U_W   = (const float*)d_in[11];
    const float* V_W   = (const float*)d_in[12];
    const float* aW1   = (const float*)d_in[13];
    const float* ab1   = (const float*)d_in[14];
    const float* aW2   = (const float*)d_in[15];
    const float* ab2   = (const float*)d_in[16];
    const float* eW1   = (const float*)d_in[17];
    const float* eb1   = (const float*)d_in[18];
    const float* eW2   = (const float*)d_in[19];
    const float* eb2   = (const float*)d_in[20];
    const float* dip_w = (const float*)d_in[21];
    float* out = (float*)d_out;

    // ---- workspace carve-up ----
    float* ws = (float*)d_ws;
    float* s    = ws;                                  // N*64
    float* vA   = s    + (size_t)N * F;                // N*192
    float* vB   = vA   + (size_t)N * F * 3;            // N*192
    float* phi  = vB   + (size_t)N * F * 3;            // N*128
    float* T    = phi  + (size_t)N * 128;              // NL*TROWS*192
    float* eacc = T    + (size_t)NL * TROWS * 192;     // B
    float* macc = eacc + B;                            // 3B
    int*   cnt  = (int*)(macc + 3 * B);                // N
    int*   off  = cnt  + N;                            // N+1
    int*   cur  = off  + N + 1;                        // N
    int*   dsts = cur  + N;                            // E

    hipMemsetAsync(cnt,  0, sizeof(int) * N, stream);
    hipMemsetAsync(eacc, 0, sizeof(float) * 4 * B, stream);
    hipMemsetAsync(out + 2 * B, 0, sizeof(float) * (size_t)N, stream); // charges

    k_init_s<<<(N * F + 255) / 256, 256, 0, stream>>>(z, emb, s);
    k_hist<<<(E + 255) / 256, 256, 0, stream>>>(ei, cnt);
    k_scan<<<1, 1024, 0, stream>>>(cnt, off, cur);
    k_scatter<<<(E + 255) / 256, 256, 0, stream>>>(ei, cur, dsts);
    k_table<<<NL * TROWS, 64, 0, stream>>>(fW1, fb1, fW2, fb2, T);

    const int gblocks = (N + 3) / 4;
    const int ublocks = (N + 31) / 32;
    // layer 0 (v == 0: skip v gather)
    k_phi<<<512, 256, 0, stream>>>(s, phi_W, phi_b, phi);
    k_gather<false><<<gblocks, 256, 0, stream>>>(pos, dsts, off, phi,
        T, nullptr, vA, s);
    k_update_mfma<<<ublocks, 256, 0, stream>>>(s, vA,
        U_W, V_W, aW1, ab1, aW2, ab2);
    // layer 1
    k_phi<<<512, 256, 0, stream>>>(s, phi_W + (size_t)192 * 64, phi_b + 192, phi);
    k_gather<true><<<gblocks, 256, 0, stream>>>(pos, dsts, off, phi,
        T + (size_t)TROWS * 192, vA, vB, s);
    k_update_mfma<<<ublocks, 256, 0, stream>>>(s, vB,
        U_W + 4096, V_W + 4096, aW1 + 8192, ab1 + F, aW2 + 12288, ab2 + 192);

    k_heads<<<(N + 255) / 256, 256, 0, stream>>>(s, vB, bidx, eW1, eb1, eW2, eb2,
                                                 dip_w, eacc, macc);
    k_final<<<1, 64, 0, stream>>>(eacc, macc, out);
}

// Round 4
// 660.639 us; speedup vs baseline: 12.0869x; 1.2148x over previous
//
#include <hip/hip_runtime.h>
#include <math.h>

static constexpr int N  = 50000;
static constexpr int E  = 800000;
static constexpr int F  = 64;
static constexpr int R  = 20;
static constexpr int NL = 2;
static constexpr int B  = 64;
static constexpr float RC   = 5.0f;
static constexpr float LN2F = 0.6931471805599453f;
static constexpr float WIDTH  = RC / (R - 1);
static constexpr float INV2W2 = 1.0f / (2.0f * WIDTH * WIDTH);
static constexpr float PI_F = 3.14159265358979323846f;

// filt(r) lookup table: NB intervals on [0,RC]
static constexpr int   NB     = 4096;
static constexpr float DR     = RC / NB;
static constexpr float INV_DR = NB / RC;
static constexpr int   TROWS  = NB + 2;   // rows computed (pairs need row i+1)
static constexpr int   TENT   = NB + 1;   // paired entries i in [0, NB]

typedef __attribute__((ext_vector_type(8))) short bf16x8;
typedef __attribute__((ext_vector_type(4))) float f32x4;

__device__ __forceinline__ float ssp_f(float x) {
    return fmaxf(x, 0.0f) + log1pf(__expf(-fabsf(x))) - LN2F;
}

__device__ __forceinline__ short f2bf(float x) {
    unsigned u = __builtin_bit_cast(unsigned, x);
    unsigned r = (u + 0x7fffu + ((u >> 16) & 1u)) >> 16;
    return (short)r;
}
__device__ __forceinline__ float bf_lo(unsigned u) {
    return __builtin_bit_cast(float, u << 16);
}
__device__ __forceinline__ float bf_hi(unsigned u) {
    return __builtin_bit_cast(float, u & 0xffff0000u);
}

__global__ void k_init_s(const int* __restrict__ z, const float* __restrict__ emb,
                         float* __restrict__ s) {
    int idx = blockIdx.x * blockDim.x + threadIdx.x;
    if (idx >= N * F) return;
    int i = idx >> 6, f = idx & 63;
    s[idx] = emb[z[i] * F + f];
}

// ---------- counting sort of edges by src + edge geometry ----------
__global__ void k_hist(const int* __restrict__ ei, int* __restrict__ cnt) {
    int e = blockIdx.x * blockDim.x + threadIdx.x;
    if (e < E) atomicAdd(&cnt[ei[e]], 1);
}

__global__ void k_scan(const int* __restrict__ cnt, int* __restrict__ off,
                       int* __restrict__ cur) {
    __shared__ int part[1024];
    const int t = threadIdx.x;
    const int CH = 49; // 1024*49 = 50176 >= N
    int s0 = 0;
    for (int j = 0; j < CH; j++) {
        int idx = t * CH + j;
        if (idx < N) s0 += cnt[idx];
    }
    part[t] = s0;
    __syncthreads();
    for (int d = 1; d < 1024; d <<= 1) {
        int v = (t >= d) ? part[t - d] : 0;
        __syncthreads();
        part[t] += v;
        __syncthreads();
    }
    int run = part[t] - s0; // exclusive prefix
    for (int j = 0; j < CH; j++) {
        int idx = t * CH + j;
        if (idx < N) {
            off[idx] = run;
            cur[idx] = run;
            run += cnt[idx];
        }
    }
    if (t == 1023) off[N] = part[1023];
}

// scatter dst + per-slot geometry {i | fr<<16, qx|qy, qz} (bf16 r_hat, u16 table idx)
__global__ void k_scatter(const int* __restrict__ ei, int* __restrict__ cur,
                          const float* __restrict__ pos,
                          int* __restrict__ dsts, unsigned* __restrict__ geom) {
    int e = blockIdx.x * blockDim.x + threadIdx.x;
    if (e >= E) return;
    int src = ei[e], dst = ei[E + e];
    int p = atomicAdd(&cur[src], 1);
    dsts[p] = dst;
    float qx = pos[dst * 3 + 0] - pos[src * 3 + 0];
    float qy = pos[dst * 3 + 1] - pos[src * 3 + 1];
    float qz = pos[dst * 3 + 2] - pos[src * 3 + 2];
    float rn = sqrtf(qx * qx + qy * qy + qz * qz);
    float invn = 1.0f / fmaxf(rn, 1e-8f);
    float t = rn * INV_DR;
    int i = (int)t;
    float fr = t - (float)i;
    if (i >= NB) { i = NB; fr = 0.0f; }   // constant region (e_ij = 0)
    unsigned ga = (unsigned)i | ((unsigned)(unsigned short)f2bf(fr) << 16);
    unsigned gb = (unsigned)(unsigned short)f2bf(qx * invn)
                | ((unsigned)(unsigned short)f2bf(qy * invn) << 16);
    unsigned gc = (unsigned)(unsigned short)f2bf(qz * invn);
    geom[(size_t)p * 3 + 0] = ga;
    geom[(size_t)p * 3 + 1] = gb;
    geom[(size_t)p * 3 + 2] = gc;
}

// ---------- filt(r) table, bf16 pair-packed: Tp[i][c] = (row i, row i+1) ----------
__global__ void k_table(const float* __restrict__ fW1, const float* __restrict__ fb1,
                        const float* __restrict__ fW2, const float* __restrict__ fb2,
                        unsigned short* __restrict__ Tp) {
    const int l   = blockIdx.x / TROWS;
    const int row = blockIdx.x % TROWS;
    const int lane = threadIdx.x; // block = 64
    const float r = fminf((float)row, (float)NB) * DR;
    const float fc = (r < RC) ? 0.5f * (__cosf(PI_F * r * (1.0f / RC)) + 1.0f) : 0.0f;

    __shared__ float sh[F];
    float acc = fb1[l * F + lane];
    const float* w1 = fW1 + (size_t)l * F * R + (size_t)lane * R;
    #pragma unroll
    for (int rr = 0; rr < R; rr++) {
        float dmu = r - rr * WIDTH;
        float er = __expf(-dmu * dmu * INV2W2) * fc;
        acc = fmaf(er, w1[rr], acc);
    }
    sh[lane] = ssp_f(acc);
    __syncthreads();
    unsigned short* TpL = Tp + (size_t)l * TENT * 384;
    #pragma unroll
    for (int p = 0; p < 3; p++) {
        int c = p * 64 + lane;
        float a = fb2[l * 192 + c];
        const float* w2 = fW2 + ((size_t)l * 192 + c) * 64;
        #pragma unroll 8
        for (int k = 0; k < F; k++) a = fmaf(sh[k], w2[k], a);
        unsigned short bf = (unsigned short)f2bf(a);
        if (row <= NB) TpL[(size_t)row * 384 + c * 2 + 0] = bf;        // entry i=row, j=0
        if (row >= 1)  TpL[(size_t)(row - 1) * 384 + c * 2 + 1] = bf;  // entry i=row-1, j=1
    }
}

// ---------- per-node packed record: [phi_s | phi_r | v0 | v1 | v2] bf16 (320 ushorts) ----------
template<bool HASV>
__launch_bounds__(256)
__global__ void k_pack(const float* __restrict__ s, const float* __restrict__ v,
                       const float* __restrict__ PW, const float* __restrict__ Pb,
                       unsigned short* __restrict__ nd) {
    __shared__ float sbuf[4][F];
    const int lane = threadIdx.x & 63;
    const int wid  = threadIdx.x >> 6;
    const int gwave = blockIdx.x * 4 + wid;
    const int nwaves = gridDim.x * 4;

    float ws[F], wr[F];
    {
        const float* rs = PW + (size_t)lane * 64;
        const float* rr = PW + (size_t)(128 + lane) * 64;
        #pragma unroll
        for (int k = 0; k < F; k += 4) {
            float4 a = *(const float4*)(rs + k);
            ws[k] = a.x; ws[k+1] = a.y; ws[k+2] = a.z; ws[k+3] = a.w;
            float4 b = *(const float4*)(rr + k);
            wr[k] = b.x; wr[k+1] = b.y; wr[k+2] = b.z; wr[k+3] = b.w;
        }
    }
    const float bs = Pb[lane], br = Pb[128 + lane];

    for (int n = gwave; n < N; n += nwaves) {
        sbuf[wid][lane] = s[(size_t)n * F + lane];
        float as = bs, ar = br;
        #pragma unroll
        for (int k = 0; k < F; k += 4) {
            float4 s4 = *(const float4*)&sbuf[wid][k];
            as = fmaf(s4.x, ws[k],   as); as = fmaf(s4.y, ws[k+1], as);
            as = fmaf(s4.z, ws[k+2], as); as = fmaf(s4.w, ws[k+3], as);
            ar = fmaf(s4.x, wr[k],   ar); ar = fmaf(s4.y, wr[k+1], ar);
            ar = fmaf(s4.z, wr[k+2], ar); ar = fmaf(s4.w, wr[k+3], ar);
        }
        unsigned short* rec = nd + (size_t)n * 320;
        rec[lane]      = (unsigned short)f2bf(as);
        rec[64 + lane] = (unsigned short)f2bf(ar);
        if (HASV) {
            #pragma unroll
            for (int d = 0; d < 3; d++)
                rec[128 + d * 64 + lane] =
                    (unsigned short)f2bf(v[((size_t)n * 3 + d) * F + lane]);
        }
    }
}

// ---------- gather/message kernel: wave per node, bf16 node records ----------
template<bool ACCUMV>
__launch_bounds__(256)
__global__ void k_gather(const int* __restrict__ dsts, const int* __restrict__ off,
                         const unsigned* __restrict__ geom,
                         const unsigned short* __restrict__ TpL,
                         const unsigned short* __restrict__ nd,
                         float* __restrict__ s, float* __restrict__ v) {
    const int lane = threadIdx.x & 63;
    const int wid  = threadIdx.x >> 6;
    const int n = blockIdx.x * 4 + wid;
    if (n >= N) return;
    const int base = off[n], end = off[n + 1];
    float ms = 0.f, mv0 = 0.f, mv1 = 0.f, mv2 = 0.f;

    for (int k = base; k < end; ++k) {
        const int dst = dsts[k];
        const unsigned ga = geom[(size_t)k * 3 + 0];
        const unsigned gb = geom[(size_t)k * 3 + 1];
        const unsigned gc = geom[(size_t)k * 3 + 2];
        const int   i  = (int)(ga & 0xffffu);
        const float fr = bf_hi(ga);
        const float rhx = bf_lo(gb), rhy = bf_hi(gb), rhz = bf_lo(gc);

        const unsigned* tp = (const unsigned*)(TpL + (size_t)i * 384);
        const unsigned us = tp[lane];
        const unsigned ur = tp[128 + lane];
        const float Ws = fmaf(fr, bf_hi(us) - bf_lo(us), bf_lo(us));
        const float Wr = fmaf(fr, bf_hi(ur) - bf_lo(ur), bf_lo(ur));

        const unsigned short* rec = nd + (size_t)dst * 320;
        const float ps = bf_lo((unsigned)rec[lane]);
        const float pr = bf_lo((unsigned)rec[64 + lane]);
        ms = fmaf(Ws, ps, ms);
        const float c = Wr * pr;
        if (ACCUMV) {
            const unsigned uv = tp[64 + lane];
            const float Wv = fmaf(fr, bf_hi(uv) - bf_lo(uv), bf_lo(uv));
            const float v0 = bf_lo((unsigned)rec[128 + lane]);
            const float v1 = bf_lo((unsigned)rec[192 + lane]);
            const float v2 = bf_lo((unsigned)rec[256 + lane]);
            mv0 = fmaf(Wv, v0, fmaf(c, rhx, mv0));
            mv1 = fmaf(Wv, v1, fmaf(c, rhy, mv1));
            mv2 = fmaf(Wv, v2, fmaf(c, rhz, mv2));
        } else {
            mv0 = fmaf(c, rhx, mv0);
            mv1 = fmaf(c, rhy, mv1);
            mv2 = fmaf(c, rhz, mv2);
        }
    }
    s[(size_t)n * F + lane] += ms;
    float* vo = v + (size_t)n * 3 * F + lane;
    if (ACCUMV) {
        vo[0]     += mv0;
        vo[F]     += mv1;
        vo[2 * F] += mv2;
    } else {
        vo[0] = mv0; vo[F] = mv1; vo[2 * F] = mv2;
    }
}

// ---------- MFMA node-update block: 64 nodes/block (2 halves of 32), 4 waves ----------
__device__ __forceinline__ bf16x8 load_wfrag(const float* __restrict__ Wp, int ldk,
                                             int nrow, int k0) {
    const float* p = Wp + (size_t)nrow * ldk + k0;
    float4 a = *(const float4*)p;
    float4 b = *(const float4*)(p + 4);
    bf16x8 r;
    r[0] = f2bf(a.x); r[1] = f2bf(a.y); r[2] = f2bf(a.z); r[3] = f2bf(a.w);
    r[4] = f2bf(b.x); r[5] = f2bf(b.y); r[6] = f2bf(b.z); r[7] = f2bf(b.w);
    return r;
}

__launch_bounds__(256)
__global__ void k_update_mfma(float* __restrict__ s, float* __restrict__ v,
                              const float* __restrict__ U_W, const float* __restrict__ V_W,
                              const float* __restrict__ aW1, const float* __restrict__ ab1,
                              const float* __restrict__ aW2, const float* __restrict__ ab2) {
    __shared__ short vlds[96 * 72];   // [row=d*32+nn][f], pad 8
    __shared__ short xlds[32 * 136];  // [nn][0:64 s | 64:128 vns], pad 8
    __shared__ short hlds[32 * 72];   // [nn][c], pad 8

    const int tid = threadIdx.x;
    const int l   = tid & 63;
    const int w   = tid >> 6;       // wave 0..3
    const int lo  = l & 15;
    const int hi  = l >> 4;         // 0..3

    // --- preload weight B-fragments (persist across both halves) ---
    bf16x8 ufr[2], vfr[2], w1fr[4], w2fr[3][2];
    #pragma unroll
    for (int kk = 0; kk < 2; kk++) {
        ufr[kk] = load_wfrag(U_W, 64, w * 16 + lo, kk * 32 + hi * 8);
        vfr[kk] = load_wfrag(V_W, 64, w * 16 + lo, kk * 32 + hi * 8);
    }
    #pragma unroll
    for (int kk = 0; kk < 4; kk++)
        w1fr[kk] = load_wfrag(aW1, 128, w * 16 + lo, kk * 32 + hi * 8);
    #pragma unroll
    for (int p = 0; p < 3; p++)
        #pragma unroll
        for (int kk = 0; kk < 2; kk++)
            w2fr[p][kk] = load_wfrag(aW2, 64, p * 64 + w * 16 + lo, kk * 32 + hi * 8);

    const float ab1c  = ab1[w * 16 + lo];
    const float ab2c0 = ab2[w * 16 + lo];
    const float ab2c1 = ab2[64 + w * 16 + lo];
    const float ab2c2 = ab2[128 + w * 16 + lo];
    const int g = w * 16 + lo;

    for (int half = 0; half < 2; half++) {
        const int n0 = blockIdx.x * 64 + half * 32;
        if (half) __syncthreads();   // protect LDS reuse

        // --- stage v (bf16) into vlds, s (bf16) into xlds[:,0:64] ---
        for (int u = tid; u < 96 * 8; u += 256) {
            int row = u >> 3, oct = u & 7;
            int d = row >> 5, nn = row & 31;
            int n = min(n0 + nn, N - 1);
            const float* src = v + ((size_t)n * 3 + d) * 64 + oct * 8;
            float4 a = *(const float4*)src;
            float4 b = *(const float4*)(src + 4);
            bf16x8 t;
            t[0] = f2bf(a.x); t[1] = f2bf(a.y); t[2] = f2bf(a.z); t[3] = f2bf(a.w);
            t[4] = f2bf(b.x); t[5] = f2bf(b.y); t[6] = f2bf(b.z); t[7] = f2bf(b.w);
            *(bf16x8*)&vlds[row * 72 + oct * 8] = t;
        }
        for (int u = tid; u < 32 * 8; u += 256) {
            int nn = u >> 3, oct = u & 7;
            int n = min(n0 + nn, N - 1);
            const float* src = s + (size_t)n * 64 + oct * 8;
            float4 a = *(const float4*)src;
            float4 b = *(const float4*)(src + 4);
            bf16x8 t;
            t[0] = f2bf(a.x); t[1] = f2bf(a.y); t[2] = f2bf(a.z); t[3] = f2bf(a.w);
            t[4] = f2bf(b.x); t[5] = f2bf(b.y); t[6] = f2bf(b.z); t[7] = f2bf(b.w);
            *(bf16x8*)&xlds[nn * 136 + oct * 8] = t;
        }
        __syncthreads();

        // --- GEMM1 ---
        f32x4 cu[6], cv[6];
        #pragma unroll
        for (int mt = 0; mt < 6; mt++) { cu[mt] = (f32x4)0.0f; cv[mt] = (f32x4)0.0f; }
        #pragma unroll
        for (int kk = 0; kk < 2; kk++) {
            #pragma unroll
            for (int mt = 0; mt < 6; mt++) {
                bf16x8 af = *(const bf16x8*)&vlds[(mt * 16 + lo) * 72 + kk * 32 + hi * 8];
                cu[mt] = __builtin_amdgcn_mfma_f32_16x16x32_bf16(af, ufr[kk], cu[mt], 0, 0, 0);
                cv[mt] = __builtin_amdgcn_mfma_f32_16x16x32_bf16(af, vfr[kk], cv[mt], 0, 0, 0);
            }
        }

        f32x4 inn[2];
        #pragma unroll
        for (int nt = 0; nt < 2; nt++) {
            #pragma unroll
            for (int r = 0; r < 4; r++) {
                float vs = 0.f, ii = 0.f;
                #pragma unroll
                for (int d = 0; d < 3; d++) {
                    float a = cu[d * 2 + nt][r], b = cv[d * 2 + nt][r];
                    vs = fmaf(b, b, vs);
                    ii = fmaf(a, b, ii);
                }
                inn[nt][r] = ii;
                int nl = nt * 16 + hi * 4 + r;
                xlds[nl * 136 + 64 + w * 16 + lo] = f2bf(vs);
            }
        }
        __syncthreads();

        // --- GEMM2 ---
        f32x4 c2[2];
        c2[0] = (f32x4)0.0f; c2[1] = (f32x4)0.0f;
        #pragma unroll
        for (int kk = 0; kk < 4; kk++) {
            #pragma unroll
            for (int mt = 0; mt < 2; mt++) {
                bf16x8 af = *(const bf16x8*)&xlds[(mt * 16 + lo) * 136 + kk * 32 + hi * 8];
                c2[mt] = __builtin_amdgcn_mfma_f32_16x16x32_bf16(af, w1fr[kk], c2[mt], 0, 0, 0);
            }
        }
        #pragma unroll
        for (int mt = 0; mt < 2; mt++)
            #pragma unroll
            for (int r = 0; r < 4; r++) {
                float hv = ssp_f(c2[mt][r] + ab1c);
                hlds[(mt * 16 + hi * 4 + r) * 72 + w * 16 + lo] = f2bf(hv);
            }
        __syncthreads();

        // --- GEMM3 ---
        f32x4 c3[2][3];
        #pragma unroll
        for (int mt = 0; mt < 2; mt++)
            #pragma unroll
            for (int p = 0; p < 3; p++) c3[mt][p] = (f32x4)0.0f;
        #pragma unroll
        for (int kk = 0; kk < 2; kk++) {
            #pragma unroll
            for (int mt = 0; mt < 2; mt++) {
                bf16x8 af = *(const bf16x8*)&hlds[(mt * 16 + lo) * 72 + kk * 32 + hi * 8];
                #pragma unroll
                for (int p = 0; p < 3; p++)
                    c3[mt][p] = __builtin_amdgcn_mfma_f32_16x16x32_bf16(af, w2fr[p][kk], c3[mt][p], 0, 0, 0);
            }
        }

        // --- epilogue ---
        #pragma unroll
        for (int mt = 0; mt < 2; mt++) {
            #pragma unroll
            for (int r = 0; r < 4; r++) {
                int n = n0 + mt * 16 + hi * 4 + r;
                if (n >= N) continue;
                float a_ss = c3[mt][0][r] + ab2c0;
                float a_sv = c3[mt][1][r] + ab2c1;
                float a_vv = c3[mt][2][r] + ab2c2;
                size_t si = (size_t)n * 64 + g;
                s[si] = s[si] + a_ss + a_sv * inn[mt][r];
                #pragma unroll
                for (int d = 0; d < 3; d++) {
                    size_t vi = ((size_t)n * 3 + d) * 64 + g;
                    v[vi] = v[vi] + a_vv * cu[d * 2 + mt][r];
                }
            }
        }
    }
}

__global__ void k_heads(const float* __restrict__ s, const float* __restrict__ v,
                        const int* __restrict__ batch_idx,
                        const float* __restrict__ eW1, const float* __restrict__ eb1,
                        const float* __restrict__ eW2, const float* __restrict__ eb2,
                        const float* __restrict__ dip_w,
                        float* __restrict__ eacc, float* __restrict__ macc) {
    __shared__ float se[B];
    __shared__ float sm[3][B];
    if (threadIdx.x < B) se[threadIdx.x] = 0.0f;
    if (threadIdx.x < 3 * B) sm[threadIdx.x >> 6][threadIdx.x & 63] = 0.0f;
    __syncthreads();
    int n = blockIdx.x * blockDim.x + threadIdx.x;
    if (n < N) {
        int b = batch_idx[n];
        float sr[F];
        #pragma unroll
        for (int f = 0; f < F; f += 4) {
            float4 t = *(const float4*)&s[(size_t)n * F + f];
            sr[f] = t.x; sr[f+1] = t.y; sr[f+2] = t.z; sr[f+3] = t.w;
        }
        float eps = eb2[0];
        for (int jj = 0; jj < F / 2; jj++) {
            float acc = eb1[jj];
            #pragma unroll
            for (int f = 0; f < F; f++)
                acc = fmaf(sr[f], eW1[jj * F + f], acc);
            eps = fmaf(eW2[jj], ssp_f(acc), eps);
        }
        atomicAdd(&se[b], eps);
        #pragma unroll
        for (int d = 0; d < 3; d++) {
            float m = 0.0f;
            #pragma unroll 8
            for (int f = 0; f < F; f++)
                m = fmaf(v[((size_t)n * 3 + d) * F + f], dip_w[f], m);
            atomicAdd(&sm[d][b], m);
        }
    }
    __syncthreads();
    if (threadIdx.x < B) atomicAdd(&eacc[threadIdx.x], se[threadIdx.x]);
    if (threadIdx.x >= B && threadIdx.x < 4 * B) {
        int d = (threadIdx.x >> 6) - 1, b = threadIdx.x & 63;
        atomicAdd(&macc[d * B + b], sm[d][b]);
    }
}

__global__ void k_final(const float* __restrict__ eacc, const float* __restrict__ macc,
                        float* __restrict__ out) {
    int b = threadIdx.x;
    if (b < B) {
        out[b] = eacc[b];
        float mx = macc[b], my = macc[B + b], mz = macc[2 * B + b];
        out[B + b] = sqrtf(mx * mx + my * my + mz * mz);
    }
}

extern "C" void kernel_launch(void* const* d_in, const int* in_sizes, int n_in,
                              void* d_out, int out_size, void* d_ws, size_t ws_size,
                              hipStream_t stream) {
    const int*   z     = (const int*)d_in[0];
    const float* pos   = (const float*)d_in[1];
    const int*   ei    = (const int*)d_in[2];
    const int*   bidx  = (const int*)d_in[3];
    const float* emb   = (const float*)d_in[4];
    const float* phi_W = (const float*)d_in[5];
    const float* phi_b = (const float*)d_in[6];
    const float* fW1   = (const float*)d_in[7];
    const float* fb1   = (const float*)d_in[8];
    const float* fW2   = (const float*)d_in[9];
    const float* fb2   = (const float*)d_in[10];
    const float* U_W   = (const float*)d_in[11];
    const float* V_W   = (const float*)d_in[12];
    const float* aW1   = (const float*)d_in[13];
    const float* ab1   = (const float*)d_in[14];
    const float* aW2   = (const float*)d_in[15];
    const float* ab2   = (const float*)d_in[16];
    const float* eW1   = (const float*)d_in[17];
    const float* eb1   = (const float*)d_in[18];
    const float* eW2   = (const float*)d_in[19];
    const float* eb2   = (const float*)d_in[20];
    const float* dip_w = (const float*)d_in[21];
    float* out = (float*)d_out;

    // ---- workspace carve-up ----
    float* ws = (float*)d_ws;
    float* s    = ws;                                  // N*64 f32
    float* v    = s + (size_t)N * F;                   // N*192 f32
    unsigned short* nd = (unsigned short*)(v + (size_t)N * F * 3);   // N*320 bf16
    unsigned short* Tp = nd + (size_t)N * 320;         // NL*TENT*384 bf16
    float* eacc = (float*)(Tp + (size_t)NL * TENT * 384); // B
    float* macc = eacc + B;                            // 3B
    int*   cnt  = (int*)(macc + 3 * B);                // N
    int*   off  = cnt  + N;                            // N+1
    int*   cur  = off  + N + 1;                        // N
    int*   dsts = cur  + N;                            // E
    unsigned* geom = (unsigned*)(dsts + E);            // 3E

    hipMemsetAsync(cnt,  0, sizeof(int) * N, stream);
    hipMemsetAsync(eacc, 0, sizeof(float) * 4 * B, stream);
    hipMemsetAsync(out + 2 * B, 0, sizeof(float) * (size_t)N, stream); // charges

    k_init_s<<<(N * F + 255) / 256, 256, 0, stream>>>(z, emb, s);
    k_hist<<<(E + 255) / 256, 256, 0, stream>>>(ei, cnt);
    k_scan<<<1, 1024, 0, stream>>>(cnt, off, cur);
    k_scatter<<<(E + 255) / 256, 256, 0, stream>>>(ei, cur, pos, dsts, geom);
    k_table<<<NL * TROWS, 64, 0, stream>>>(fW1, fb1, fW2, fb2, Tp);

    const int gblocks = (N + 3) / 4;
    const int ublocks = (N + 63) / 64;
    // layer 0 (v == 0: no v planes, v written not accumulated)
    k_pack<false><<<512, 256, 0, stream>>>(s, nullptr, phi_W, phi_b, nd);
    k_gather<false><<<gblocks, 256, 0, stream>>>(dsts, off, geom, Tp, nd, s, v);
    k_update_mfma<<<ublocks, 256, 0, stream>>>(s, v,
        U_W, V_W, aW1, ab1, aW2, ab2);
    // layer 1
    k_pack<true><<<512, 256, 0, stream>>>(s, v, phi_W + (size_t)192 * 64, phi_b + 192, nd);
    k_gather<true><<<gblocks, 256, 0, stream>>>(dsts, off, geom,
        Tp + (size_t)TENT * 384, nd, s, v);
    k_update_mfma<<<ublocks, 256, 0, stream>>>(s, v,
        U_W + 4096, V_W + 4096, aW1 + 8192, ab1 + F, aW2 + 12288, ab2 + 192);

    k_heads<<<(N + 255) / 256, 256, 0, stream>>>(s, v, bidx, eW1, eb1, eW2, eb2,
                                                 dip_w, eacc, macc);
    k_final<<<1, 64, 0, stream>>>(eacc, macc, out);
}

// Round 5
// 535.308 us; speedup vs baseline: 14.9168x; 1.2341x over previous
//
#include <hip/hip_runtime.h>
#include <math.h>

static constexpr int N  = 50000;
static constexpr int E  = 800000;
static constexpr int F  = 64;
static constexpr int R  = 20;
static constexpr int NL = 2;
static constexpr int B  = 64;
static constexpr float RC   = 5.0f;
static constexpr float LN2F = 0.6931471805599453f;
static constexpr float WIDTH  = RC / (R - 1);
static constexpr float INV2W2 = 1.0f / (2.0f * WIDTH * WIDTH);
static constexpr float PI_F = 3.14159265358979323846f;

// filt(r) lookup table: NB intervals on [0,RC]
static constexpr int   NB     = 4096;
static constexpr float DR     = RC / NB;
static constexpr float INV_DR = NB / RC;
static constexpr int   TROWS  = NB + 2;   // rows computed (pairs need row i+1)
static constexpr int   TENT   = NB + 1;   // paired entries i in [0, NB]

static constexpr int NBLK_SCAN = (N + 255) / 256;  // 196

typedef __attribute__((ext_vector_type(8))) short bf16x8;
typedef __attribute__((ext_vector_type(4))) float f32x4;

__device__ __forceinline__ float ssp_f(float x) {
    return fmaxf(x, 0.0f) + log1pf(__expf(-fabsf(x))) - LN2F;
}

__device__ __forceinline__ short f2bf(float x) {
    unsigned u = __builtin_bit_cast(unsigned, x);
    unsigned r = (u + 0x7fffu + ((u >> 16) & 1u)) >> 16;
    return (short)r;
}
__device__ __forceinline__ float bf_lo(unsigned u) {
    return __builtin_bit_cast(float, u << 16);
}
__device__ __forceinline__ float bf_hi(unsigned u) {
    return __builtin_bit_cast(float, u & 0xffff0000u);
}

// ---------- counting sort of edges by src + edge geometry ----------
__global__ void k_hist(const int* __restrict__ ei, int* __restrict__ cnt) {
    int e = blockIdx.x * blockDim.x + threadIdx.x;
    if (e < E) atomicAdd(&cnt[ei[e]], 1);
}

// phase A: per-block sums of cnt
__global__ void k_scan_a(const int* __restrict__ cnt, int* __restrict__ bsum) {
    __shared__ int part[256];
    const int t = threadIdx.x;
    const int idx = blockIdx.x * 256 + t;
    int v = (idx < N) ? cnt[idx] : 0;
    part[t] = v;
    __syncthreads();
    for (int d = 1; d < 256; d <<= 1) {
        int x = (t >= d) ? part[t - d] : 0;
        __syncthreads();
        part[t] += x;
        __syncthreads();
    }
    if (t == 255) bsum[blockIdx.x] = part[255];
}

// phase B: scan the 196 block sums (single block of 256)
__global__ void k_scan_b(const int* __restrict__ bsum, int* __restrict__ bpre,
                         int* __restrict__ offN) {
    __shared__ int part[256];
    const int t = threadIdx.x;
    int v = (t < NBLK_SCAN) ? bsum[t] : 0;
    part[t] = v;
    __syncthreads();
    for (int d = 1; d < 256; d <<= 1) {
        int x = (t >= d) ? part[t - d] : 0;
        __syncthreads();
        part[t] += x;
        __syncthreads();
    }
    if (t < NBLK_SCAN) bpre[t] = part[t] - v;   // exclusive
    if (t == NBLK_SCAN - 1) *offN = part[t];    // off[N] = total (== E)
}

// phase C: block-local exclusive scan + base
__global__ void k_scan_c(const int* __restrict__ cnt, const int* __restrict__ bpre,
                         int* __restrict__ off, int* __restrict__ cur) {
    __shared__ int part[256];
    const int t = threadIdx.x;
    const int idx = blockIdx.x * 256 + t;
    int v = (idx < N) ? cnt[idx] : 0;
    part[t] = v;
    __syncthreads();
    for (int d = 1; d < 256; d <<= 1) {
        int x = (t >= d) ? part[t - d] : 0;
        __syncthreads();
        part[t] += x;
        __syncthreads();
    }
    if (idx < N) {
        int e = bpre[blockIdx.x] + part[t] - v;
        off[idx] = e;
        cur[idx] = e;
    }
}

// scatter one 16B record per CSR slot: {dst, i|fr<<16, qx|qy, qz}
__global__ void k_scatter(const int* __restrict__ ei, int* __restrict__ cur,
                          const float* __restrict__ pos, uint4* __restrict__ edata) {
    int e = blockIdx.x * blockDim.x + threadIdx.x;
    if (e >= E) return;
    int src = ei[e], dst = ei[E + e];
    int p = atomicAdd(&cur[src], 1);
    float qx = pos[dst * 3 + 0] - pos[src * 3 + 0];
    float qy = pos[dst * 3 + 1] - pos[src * 3 + 1];
    float qz = pos[dst * 3 + 2] - pos[src * 3 + 2];
    float rn = sqrtf(qx * qx + qy * qy + qz * qz);
    float invn = 1.0f / fmaxf(rn, 1e-8f);
    float t = rn * INV_DR;
    int i = (int)t;
    float fr = t - (float)i;
    if (i >= NB) { i = NB; fr = 0.0f; }   // constant region (e_ij = 0)
    uint4 rec;
    rec.x = (unsigned)dst;
    rec.y = (unsigned)i | ((unsigned)(unsigned short)f2bf(fr) << 16);
    rec.z = (unsigned)(unsigned short)f2bf(qx * invn)
          | ((unsigned)(unsigned short)f2bf(qy * invn) << 16);
    rec.w = (unsigned)(unsigned short)f2bf(qz * invn);
    edata[p] = rec;
}

// ---------- filt(r) table, bf16 pair-packed: Tp[i][c] = (row i, row i+1) ----------
__global__ void k_table(const float* __restrict__ fW1, const float* __restrict__ fb1,
                        const float* __restrict__ fW2, const float* __restrict__ fb2,
                        unsigned short* __restrict__ Tp) {
    const int l   = blockIdx.x / TROWS;
    const int row = blockIdx.x % TROWS;
    const int lane = threadIdx.x; // block = 64
    const float r = fminf((float)row, (float)NB) * DR;
    const float fc = (r < RC) ? 0.5f * (__cosf(PI_F * r * (1.0f / RC)) + 1.0f) : 0.0f;

    __shared__ float sh[F];
    float acc = fb1[l * F + lane];
    const float* w1 = fW1 + (size_t)l * F * R + (size_t)lane * R;
    #pragma unroll
    for (int rr = 0; rr < R; rr++) {
        float dmu = r - rr * WIDTH;
        float er = __expf(-dmu * dmu * INV2W2) * fc;
        acc = fmaf(er, w1[rr], acc);
    }
    sh[lane] = ssp_f(acc);
    __syncthreads();
    unsigned short* TpL = Tp + (size_t)l * TENT * 384;
    #pragma unroll
    for (int p = 0; p < 3; p++) {
        int c = p * 64 + lane;
        float a = fb2[l * 192 + c];
        const float* w2 = fW2 + ((size_t)l * 192 + c) * 64;
        #pragma unroll 8
        for (int k = 0; k < F; k++) a = fmaf(sh[k], w2[k], a);
        unsigned short bf = (unsigned short)f2bf(a);
        if (row <= NB) TpL[(size_t)row * 384 + c * 2 + 0] = bf;        // entry i=row, j=0
        if (row >= 1)  TpL[(size_t)(row - 1) * 384 + c * 2 + 1] = bf;  // entry i=row-1, j=1
    }
}

// ---------- per-node packed record: [phi_s | phi_r | v0 | v1 | v2] bf16 (320 ushorts) ----------
// HASV=false: also INITIALIZES s from emb[z] (layer 0 fusion).
template<bool HASV>
__launch_bounds__(256)
__global__ void k_pack(float* __restrict__ s, const float* __restrict__ v,
                       const int* __restrict__ z, const float* __restrict__ emb,
                       const float* __restrict__ PW, const float* __restrict__ Pb,
                       unsigned short* __restrict__ nd) {
    __shared__ float sbuf[4][F];
    const int lane = threadIdx.x & 63;
    const int wid  = threadIdx.x >> 6;
    const int gwave = blockIdx.x * 4 + wid;
    const int nwaves = gridDim.x * 4;

    float ws[F], wr[F];
    {
        const float* rs = PW + (size_t)lane * 64;
        const float* rr = PW + (size_t)(128 + lane) * 64;
        #pragma unroll
        for (int k = 0; k < F; k += 4) {
            float4 a = *(const float4*)(rs + k);
            ws[k] = a.x; ws[k+1] = a.y; ws[k+2] = a.z; ws[k+3] = a.w;
            float4 b = *(const float4*)(rr + k);
            wr[k] = b.x; wr[k+1] = b.y; wr[k+2] = b.z; wr[k+3] = b.w;
        }
    }
    const float bs = Pb[lane], br = Pb[128 + lane];

    for (int n = gwave; n < N; n += nwaves) {
        float sv;
        if (HASV) {
            sv = s[(size_t)n * F + lane];
        } else {
            sv = emb[(size_t)z[n] * F + lane];
            s[(size_t)n * F + lane] = sv;      // initialize s
        }
        sbuf[wid][lane] = sv;
        float as = bs, ar = br;
        #pragma unroll
        for (int k = 0; k < F; k += 4) {
            float4 s4 = *(const float4*)&sbuf[wid][k];
            as = fmaf(s4.x, ws[k],   as); as = fmaf(s4.y, ws[k+1], as);
            as = fmaf(s4.z, ws[k+2], as); as = fmaf(s4.w, ws[k+3], as);
            ar = fmaf(s4.x, wr[k],   ar); ar = fmaf(s4.y, wr[k+1], ar);
            ar = fmaf(s4.z, wr[k+2], ar); ar = fmaf(s4.w, wr[k+3], ar);
        }
        unsigned short* rec = nd + (size_t)n * 320;
        rec[lane]      = (unsigned short)f2bf(as);
        rec[64 + lane] = (unsigned short)f2bf(ar);
        if (HASV) {
            #pragma unroll
            for (int d = 0; d < 3; d++)
                rec[128 + d * 64 + lane] =
                    (unsigned short)f2bf(v[((size_t)n * 3 + d) * F + lane]);
        }
    }
}

// ---------- gather/message kernel: wave per node, bf16 node records ----------
template<bool ACCUMV>
__launch_bounds__(256)
__global__ void k_gather(const uint4* __restrict__ edata, const int* __restrict__ off,
                         const unsigned short* __restrict__ TpL,
                         const unsigned short* __restrict__ nd,
                         float* __restrict__ s, float* __restrict__ v) {
    const int lane = threadIdx.x & 63;
    const int wid  = threadIdx.x >> 6;
    const int n = blockIdx.x * 4 + wid;
    if (n >= N) return;
    const int base = off[n], end = off[n + 1];
    float ms = 0.f, mv0 = 0.f, mv1 = 0.f, mv2 = 0.f;

    for (int k = base; k < end; ++k) {
        const uint4 ed = edata[k];
        const int dst = (int)ed.x;
        const int   i  = (int)(ed.y & 0xffffu);
        const float fr = bf_hi(ed.y);
        const float rhx = bf_lo(ed.z), rhy = bf_hi(ed.z), rhz = bf_lo(ed.w);

        const unsigned* tp = (const unsigned*)(TpL + (size_t)i * 384);
        const unsigned us = tp[lane];
        const unsigned ur = tp[128 + lane];
        const float Ws = fmaf(fr, bf_hi(us) - bf_lo(us), bf_lo(us));
        const float Wr = fmaf(fr, bf_hi(ur) - bf_lo(ur), bf_lo(ur));

        const unsigned short* rec = nd + (size_t)dst * 320;
        const float ps = bf_lo((unsigned)rec[lane]);
        const float pr = bf_lo((unsigned)rec[64 + lane]);
        ms = fmaf(Ws, ps, ms);
        const float c = Wr * pr;
        if (ACCUMV) {
            const unsigned uv = tp[64 + lane];
            const float Wv = fmaf(fr, bf_hi(uv) - bf_lo(uv), bf_lo(uv));
            const float v0 = bf_lo((unsigned)rec[128 + lane]);
            const float v1 = bf_lo((unsigned)rec[192 + lane]);
            const float v2 = bf_lo((unsigned)rec[256 + lane]);
            mv0 = fmaf(Wv, v0, fmaf(c, rhx, mv0));
            mv1 = fmaf(Wv, v1, fmaf(c, rhy, mv1));
            mv2 = fmaf(Wv, v2, fmaf(c, rhz, mv2));
        } else {
            mv0 = fmaf(c, rhx, mv0);
            mv1 = fmaf(c, rhy, mv1);
            mv2 = fmaf(c, rhz, mv2);
        }
    }
    s[(size_t)n * F + lane] += ms;
    float* vo = v + (size_t)n * 3 * F + lane;
    if (ACCUMV) {
        vo[0]     += mv0;
        vo[F]     += mv1;
        vo[2 * F] += mv2;
    } else {
        vo[0] = mv0; vo[F] = mv1; vo[2 * F] = mv2;
    }
}

// ---------- MFMA node-update block: 64 nodes/block (2 halves of 32), 4 waves ----------
__device__ __forceinline__ bf16x8 load_wfrag(const float* __restrict__ Wp, int ldk,
                                             int nrow, int k0) {
    const float* p = Wp + (size_t)nrow * ldk + k0;
    float4 a = *(const float4*)p;
    float4 b = *(const float4*)(p + 4);
    bf16x8 r;
    r[0] = f2bf(a.x); r[1] = f2bf(a.y); r[2] = f2bf(a.z); r[3] = f2bf(a.w);
    r[4] = f2bf(b.x); r[5] = f2bf(b.y); r[6] = f2bf(b.z); r[7] = f2bf(b.w);
    return r;
}

__launch_bounds__(256)
__global__ void k_update_mfma(float* __restrict__ s, float* __restrict__ v,
                              const float* __restrict__ U_W, const float* __restrict__ V_W,
                              const float* __restrict__ aW1, const float* __restrict__ ab1,
                              const float* __restrict__ aW2, const float* __restrict__ ab2) {
    __shared__ short vlds[96 * 72];   // [row=d*32+nn][f], pad 8
    __shared__ short xlds[32 * 136];  // [nn][0:64 s | 64:128 vns], pad 8
    __shared__ short hlds[32 * 72];   // [nn][c], pad 8

    const int tid = threadIdx.x;
    const int l   = tid & 63;
    const int w   = tid >> 6;       // wave 0..3
    const int lo  = l & 15;
    const int hi  = l >> 4;         // 0..3

    // --- preload weight B-fragments (persist across both halves) ---
    bf16x8 ufr[2], vfr[2], w1fr[4], w2fr[3][2];
    #pragma unroll
    for (int kk = 0; kk < 2; kk++) {
        ufr[kk] = load_wfrag(U_W, 64, w * 16 + lo, kk * 32 + hi * 8);
        vfr[kk] = load_wfrag(V_W, 64, w * 16 + lo, kk * 32 + hi * 8);
    }
    #pragma unroll
    for (int kk = 0; kk < 4; kk++)
        w1fr[kk] = load_wfrag(aW1, 128, w * 16 + lo, kk * 32 + hi * 8);
    #pragma unroll
    for (int p = 0; p < 3; p++)
        #pragma unroll
        for (int kk = 0; kk < 2; kk++)
            w2fr[p][kk] = load_wfrag(aW2, 64, p * 64 + w * 16 + lo, kk * 32 + hi * 8);

    const float ab1c  = ab1[w * 16 + lo];
    const float ab2c0 = ab2[w * 16 + lo];
    const float ab2c1 = ab2[64 + w * 16 + lo];
    const float ab2c2 = ab2[128 + w * 16 + lo];
    const int g = w * 16 + lo;

    for (int half = 0; half < 2; half++) {
        const int n0 = blockIdx.x * 64 + half * 32;
        if (half) __syncthreads();   // protect LDS reuse

        // --- stage v (bf16) into vlds, s (bf16) into xlds[:,0:64] ---
        for (int u = tid; u < 96 * 8; u += 256) {
            int row = u >> 3, oct = u & 7;
            int d = row >> 5, nn = row & 31;
            int n = min(n0 + nn, N - 1);
            const float* src = v + ((size_t)n * 3 + d) * 64 + oct * 8;
            float4 a = *(const float4*)src;
            float4 b = *(const float4*)(src + 4);
            bf16x8 t;
            t[0] = f2bf(a.x); t[1] = f2bf(a.y); t[2] = f2bf(a.z); t[3] = f2bf(a.w);
            t[4] = f2bf(b.x); t[5] = f2bf(b.y); t[6] = f2bf(b.z); t[7] = f2bf(b.w);
            *(bf16x8*)&vlds[row * 72 + oct * 8] = t;
        }
        for (int u = tid; u < 32 * 8; u += 256) {
            int nn = u >> 3, oct = u & 7;
            int n = min(n0 + nn, N - 1);
            const float* src = s + (size_t)n * 64 + oct * 8;
            float4 a = *(const float4*)src;
            float4 b = *(const float4*)(src + 4);
            bf16x8 t;
            t[0] = f2bf(a.x); t[1] = f2bf(a.y); t[2] = f2bf(a.z); t[3] = f2bf(a.w);
            t[4] = f2bf(b.x); t[5] = f2bf(b.y); t[6] = f2bf(b.z); t[7] = f2bf(b.w);
            *(bf16x8*)&xlds[nn * 136 + oct * 8] = t;
        }
        __syncthreads();

        // --- GEMM1 ---
        f32x4 cu[6], cv[6];
        #pragma unroll
        for (int mt = 0; mt < 6; mt++) { cu[mt] = (f32x4)0.0f; cv[mt] = (f32x4)0.0f; }
        #pragma unroll
        for (int kk = 0; kk < 2; kk++) {
            #pragma unroll
            for (int mt = 0; mt < 6; mt++) {
                bf16x8 af = *(const bf16x8*)&vlds[(mt * 16 + lo) * 72 + kk * 32 + hi * 8];
                cu[mt] = __builtin_amdgcn_mfma_f32_16x16x32_bf16(af, ufr[kk], cu[mt], 0, 0, 0);
                cv[mt] = __builtin_amdgcn_mfma_f32_16x16x32_bf16(af, vfr[kk], cv[mt], 0, 0, 0);
            }
        }

        f32x4 inn[2];
        #pragma unroll
        for (int nt = 0; nt < 2; nt++) {
            #pragma unroll
            for (int r = 0; r < 4; r++) {
                float vs = 0.f, ii = 0.f;
                #pragma unroll
                for (int d = 0; d < 3; d++) {
                    float a = cu[d * 2 + nt][r], b = cv[d * 2 + nt][r];
                    vs = fmaf(b, b, vs);
                    ii = fmaf(a, b, ii);
                }
                inn[nt][r] = ii;
                int nl = nt * 16 + hi * 4 + r;
                xlds[nl * 136 + 64 + w * 16 + lo] = f2bf(vs);
            }
        }
        __syncthreads();

        // --- GEMM2 ---
        f32x4 c2[2];
        c2[0] = (f32x4)0.0f; c2[1] = (f32x4)0.0f;
        #pragma unroll
        for (int kk = 0; kk < 4; kk++) {
            #pragma unroll
            for (int mt = 0; mt < 2; mt++) {
                bf16x8 af = *(const bf16x8*)&xlds[(mt * 16 + lo) * 136 + kk * 32 + hi * 8];
                c2[mt] = __builtin_amdgcn_mfma_f32_16x16x32_bf16(af, w1fr[kk], c2[mt], 0, 0, 0);
            }
        }
        #pragma unroll
        for (int mt = 0; mt < 2; mt++)
            #pragma unroll
            for (int r = 0; r < 4; r++) {
                float hv = ssp_f(c2[mt][r] + ab1c);
                hlds[(mt * 16 + hi * 4 + r) * 72 + w * 16 + lo] = f2bf(hv);
            }
        __syncthreads();

        // --- GEMM3 ---
        f32x4 c3[2][3];
        #pragma unroll
        for (int mt = 0; mt < 2; mt++)
            #pragma unroll
            for (int p = 0; p < 3; p++) c3[mt][p] = (f32x4)0.0f;
        #pragma unroll
        for (int kk = 0; kk < 2; kk++) {
            #pragma unroll
            for (int mt = 0; mt < 2; mt++) {
                bf16x8 af = *(const bf16x8*)&hlds[(mt * 16 + lo) * 72 + kk * 32 + hi * 8];
                #pragma unroll
                for (int p = 0; p < 3; p++)
                    c3[mt][p] = __builtin_amdgcn_mfma_f32_16x16x32_bf16(af, w2fr[p][kk], c3[mt][p], 0, 0, 0);
            }
        }

        // --- epilogue ---
        #pragma unroll
        for (int mt = 0; mt < 2; mt++) {
            #pragma unroll
            for (int r = 0; r < 4; r++) {
                int n = n0 + mt * 16 + hi * 4 + r;
                if (n >= N) continue;
                float a_ss = c3[mt][0][r] + ab2c0;
                float a_sv = c3[mt][1][r] + ab2c1;
                float a_vv = c3[mt][2][r] + ab2c2;
                size_t si = (size_t)n * 64 + g;
                s[si] = s[si] + a_ss + a_sv * inn[mt][r];
                #pragma unroll
                for (int d = 0; d < 3; d++) {
                    size_t vi = ((size_t)n * 3 + d) * 64 + g;
                    v[vi] = v[vi] + a_vv * cu[d * 2 + mt][r];
                }
            }
        }
    }
}

__global__ void k_heads(const float* __restrict__ s, const float* __restrict__ v,
                        const int* __restrict__ batch_idx,
                        const float* __restrict__ eW1, const float* __restrict__ eb1,
                        const float* __restrict__ eW2, const float* __restrict__ eb2,
                        const float* __restrict__ dip_w,
                        float* __restrict__ eacc, float* __restrict__ macc) {
    __shared__ float se[B];
    __shared__ float sm[3][B];
    if (threadIdx.x < B) se[threadIdx.x] = 0.0f;
    if (threadIdx.x < 3 * B) sm[threadIdx.x >> 6][threadIdx.x & 63] = 0.0f;
    __syncthreads();
    int n = blockIdx.x * blockDim.x + threadIdx.x;
    if (n < N) {
        int b = batch_idx[n];
        float sr[F];
        #pragma unroll
        for (int f = 0; f < F; f += 4) {
            float4 t = *(const float4*)&s[(size_t)n * F + f];
            sr[f] = t.x; sr[f+1] = t.y; sr[f+2] = t.z; sr[f+3] = t.w;
        }
        float eps = eb2[0];
        for (int jj = 0; jj < F / 2; jj++) {
            float acc = eb1[jj];
            #pragma unroll
            for (int f = 0; f < F; f++)
                acc = fmaf(sr[f], eW1[jj * F + f], acc);
            eps = fmaf(eW2[jj], ssp_f(acc), eps);
        }
        atomicAdd(&se[b], eps);
        #pragma unroll
        for (int d = 0; d < 3; d++) {
            float m = 0.0f;
            #pragma unroll 8
            for (int f = 0; f < F; f++)
                m = fmaf(v[((size_t)n * 3 + d) * F + f], dip_w[f], m);
            atomicAdd(&sm[d][b], m);
        }
    }
    __syncthreads();
    if (threadIdx.x < B) atomicAdd(&eacc[threadIdx.x], se[threadIdx.x]);
    if (threadIdx.x >= B && threadIdx.x < 4 * B) {
        int d = (threadIdx.x >> 6) - 1, b = threadIdx.x & 63;
        atomicAdd(&macc[d * B + b], sm[d][b]);
    }
}

__global__ void k_final(const float* __restrict__ eacc, const float* __restrict__ macc,
                        float* __restrict__ out) {
    int b = threadIdx.x;
    if (b < B) {
        out[b] = eacc[b];
        float mx = macc[b], my = macc[B + b], mz = macc[2 * B + b];
        out[B + b] = sqrtf(mx * mx + my * my + mz * mz);
    }
}

extern "C" void kernel_launch(void* const* d_in, const int* in_sizes, int n_in,
                              void* d_out, int out_size, void* d_ws, size_t ws_size,
                              hipStream_t stream) {
    const int*   z     = (const int*)d_in[0];
    const float* pos   = (const float*)d_in[1];
    const int*   ei    = (const int*)d_in[2];
    const int*   bidx  = (const int*)d_in[3];
    const float* emb   = (const float*)d_in[4];
    const float* phi_W = (const float*)d_in[5];
    const float* phi_b = (const float*)d_in[6];
    const float* fW1   = (const float*)d_in[7];
    const float* fb1   = (const float*)d_in[8];
    const float* fW2   = (const float*)d_in[9];
    const float* fb2   = (const float*)d_in[10];
    const float* U_W   = (const float*)d_in[11];
    const float* V_W   = (const float*)d_in[12];
    const float* aW1   = (const float*)d_in[13];
    const float* ab1   = (const float*)d_in[14];
    const float* aW2   = (const float*)d_in[15];
    const float* ab2   = (const float*)d_in[16];
    const float* eW1   = (const float*)d_in[17];
    const float* eb1   = (const float*)d_in[18];
    const float* eW2   = (const float*)d_in[19];
    const float* eb2   = (const float*)d_in[20];
    const float* dip_w = (const float*)d_in[21];
    float* out = (float*)d_out;

    // ---- workspace carve-up ----
    float* ws = (float*)d_ws;
    float* s    = ws;                                  // N*64 f32
    float* v    = s + (size_t)N * F;                   // N*192 f32
    unsigned short* nd = (unsigned short*)(v + (size_t)N * F * 3);   // N*320 bf16
    unsigned short* Tp = nd + (size_t)N * 320;         // NL*TENT*384 bf16
    float* eacc = (float*)(Tp + (size_t)NL * TENT * 384); // B
    float* macc = eacc + B;                            // 3B
    int*   cnt  = (int*)(macc + 3 * B);                // N
    int*   off  = cnt  + N;                            // N+1
    int*   cur  = off  + N + 1;                        // N
    int*   bsum = cur  + N;                            // 256
    int*   bpre = bsum + 256;                          // 256
    uint4* edata = (uint4*)(((uintptr_t)(bpre + 256) + 15) & ~(uintptr_t)15); // E*16B

    hipMemsetAsync(cnt,  0, sizeof(int) * N, stream);
    hipMemsetAsync(eacc, 0, sizeof(float) * 4 * B, stream);
    hipMemsetAsync(out + 2 * B, 0, sizeof(float) * (size_t)N, stream); // charges

    k_hist<<<(E + 255) / 256, 256, 0, stream>>>(ei, cnt);
    k_scan_a<<<NBLK_SCAN, 256, 0, stream>>>(cnt, bsum);
    k_scan_b<<<1, 256, 0, stream>>>(bsum, bpre, off + N);
    k_scan_c<<<NBLK_SCAN, 256, 0, stream>>>(cnt, bpre, off, cur);
    k_scatter<<<(E + 255) / 256, 256, 0, stream>>>(ei, cur, pos, edata);
    k_table<<<NL * TROWS, 64, 0, stream>>>(fW1, fb1, fW2, fb2, Tp);

    const int gblocks = (N + 3) / 4;
    const int ublocks = (N + 63) / 64;
    // layer 0 (pack also initializes s from emb[z]; v written not accumulated)
    k_pack<false><<<512, 256, 0, stream>>>(s, nullptr, z, emb, phi_W, phi_b, nd);
    k_gather<false><<<gblocks, 256, 0, stream>>>(edata, off, Tp, nd, s, v);
    k_update_mfma<<<ublocks, 256, 0, stream>>>(s, v,
        U_W, V_W, aW1, ab1, aW2, ab2);
    // layer 1
    k_pack<true><<<512, 256, 0, stream>>>(s, v, z, emb, phi_W + (size_t)192 * 64,
                                          phi_b + 192, nd);
    k_gather<true><<<gblocks, 256, 0, stream>>>(edata, off,
        Tp + (size_t)TENT * 384, nd, s, v);
    k_update_mfma<<<ublocks, 256, 0, stream>>>(s, v,
        U_W + 4096, V_W + 4096, aW1 + 8192, ab1 + F, aW2 + 12288, ab2 + 192);

    k_heads<<<(N + 255) / 256, 256, 0, stream>>>(s, v, bidx, eW1, eb1, eW2, eb2,
                                                 dip_w, eacc, macc);
    k_final<<<1, 64, 0, stream>>>(eacc, macc, out);
}